// Round 9
// baseline (193.847 us; speedup 1.0000x reference)
//
#include <hip/hip_runtime.h>
#include <hip/hip_bf16.h>

typedef __bf16 bf16x8 __attribute__((ext_vector_type(8)));
typedef float f32x4 __attribute__((ext_vector_type(4)));
typedef float f32x16 __attribute__((ext_vector_type(16)));
typedef unsigned short u16;
typedef unsigned int u32;
typedef unsigned long long u64;
typedef u32 u32x4v __attribute__((ext_vector_type(4)));

#define QSCALE 0.18033688011112042f  /* log2(e)/8 : folds SCALE and exp->exp2 into Q */

__device__ __forceinline__ u16 f2b(float x) {
  __hip_bfloat16 h = __float2bfloat16(x);
  return __builtin_bit_cast(u16, h);
}

__device__ __forceinline__ float b2f(u16 x) {
  u32 u = ((u32)x) << 16;
  return __builtin_bit_cast(float, u);
}

__device__ __forceinline__ float exp2_fast(float x) {
#if __has_builtin(__builtin_amdgcn_exp2f)
  return __builtin_amdgcn_exp2f(x);
#else
  float r; asm("v_exp_f32 %0, %1" : "=v"(r) : "v"(x)); return r;
#endif
}

// async global->LDS, 16B per lane; LDS dest = wave-uniform base + lane*16
__device__ __forceinline__ void gload_lds16(const void* g, void* l) {
  __builtin_amdgcn_global_load_lds((const __attribute__((address_space(1))) u32*)g,
                                   (__attribute__((address_space(3))) u32*)l, 16, 0, 0);
}

// ---------------- cast f32 -> bf16 (4 elems/thread) ----------------
__global__ __launch_bounds__(256) void cast_bf16_kernel(const float* __restrict__ src,
                                                        u16* __restrict__ dst, int n4) {
  int i = blockIdx.x * 256 + threadIdx.x;
  if (i >= n4) return;
  float4 v = ((const float4*)src)[i];
  ushort4 o;
  o.x = f2b(v.x); o.y = f2b(v.y); o.z = f2b(v.z); o.w = f2b(v.w);
  ((ushort4*)dst)[i] = o;
}

// ---------------- transpose+cast: src [R][C] f32 -> dst [C][R] bf16 ----------------
__global__ __launch_bounds__(256) void transpose_cast_kernel(const float* __restrict__ src,
                                                             u16* __restrict__ dst,
                                                             int R, int C) {
  __shared__ float t[32][33];
  int c0 = blockIdx.x * 32, r0 = blockIdx.y * 32;
  int tx = threadIdx.x, ty = threadIdx.y;
  for (int k = 0; k < 32; k += 8)
    t[ty + k][tx] = src[(size_t)(r0 + ty + k) * C + c0 + tx];
  __syncthreads();
  for (int k = 0; k < 32; k += 8)
    dst[(size_t)(c0 + ty + k) * R + r0 + tx] = f2b(t[tx][ty + k]);
}

// ---------------- mask [2048][2048] int32 -> bit-packed u64 words ----------------
__global__ __launch_bounds__(256) void maskbits_kernel(const int* __restrict__ mask,
                                                       u64* __restrict__ bits) {
  int gtid = blockIdx.x * 256 + threadIdx.x;
  int wid = gtid >> 6, lane = gtid & 63;
  int v = mask[(size_t)wid * 64 + lane];
  u64 b = __ballot(v != 0);
  if (lane == 0) bits[wid] = b;
}

// ---------------- QKV GEMM: xb[4096][1024] @ Wqkv_t[3072][1024]^T ----------------
// m97 structure: global_load_lds(16B) staging, 2 barriers per K-step.
// Epilogue scatters into Qb (pre-scaled by QSCALE) / Kb [B][H][N][64], Vt [B][H][64][N].
__global__ __launch_bounds__(256) void gemm_qkv_kernel(const u16* __restrict__ A,
                                                       const u16* __restrict__ Bt,
                                                       u16* __restrict__ Qb,
                                                       u16* __restrict__ Kb,
                                                       u16* __restrict__ Vt) {
  __shared__ u16 lA[128 * 32], lB[128 * 32];
  const int tid = threadIdx.x, lane = tid & 63, w = tid >> 6;
  const int wr = w >> 1, wc = w & 1, lrow = lane & 15, lk = lane >> 4;
  const int bm = blockIdx.y, bn = blockIdx.x;
  const int srow = tid >> 2, scol = (tid & 3) * 8;
  const u16* Arow = A + (size_t)(bm * 128 + srow) * 1024 + scol;
  const u16* Brow = Bt + (size_t)(bn * 128 + srow) * 1024 + scol;
  f32x4 acc[4][4] = {};
  for (int k0 = 0; k0 < 1024; k0 += 32) {
    __syncthreads();  // prior iteration's ds_reads done before overwrite
    gload_lds16(Arow + k0,             (char*)lA + w * 1024);
    gload_lds16(Arow + 64 * 1024 + k0, (char*)lA + 4096 + w * 1024);
    gload_lds16(Brow + k0,             (char*)lB + w * 1024);
    gload_lds16(Brow + 64 * 1024 + k0, (char*)lB + 4096 + w * 1024);
    __syncthreads();  // drains vmcnt: staged data visible
    bf16x8 af[4], bfr[4];
    for (int mi = 0; mi < 4; mi++)
      af[mi] = *(const bf16x8*)&lA[(wr * 64 + mi * 16 + lrow) * 32 + lk * 8];
    for (int ni = 0; ni < 4; ni++)
      bfr[ni] = *(const bf16x8*)&lB[(wc * 64 + ni * 16 + lrow) * 32 + lk * 8];
    for (int mi = 0; mi < 4; mi++)
      for (int ni = 0; ni < 4; ni++)
        acc[mi][ni] = __builtin_amdgcn_mfma_f32_16x16x32_bf16(af[mi], bfr[ni], acc[mi][ni], 0, 0, 0);
  }
  const int rowbase = bm * 128 + wr * 64;
  const int colbase = bn * 128 + wc * 64;
  for (int mi = 0; mi < 4; mi++)
    for (int ni = 0; ni < 4; ni++)
      for (int r = 0; r < 4; r++) {
        int row = rowbase + mi * 16 + lk * 4 + r;
        int col = colbase + ni * 16 + lrow;
        int b = row >> 11, n = row & 2047;
        int which = col >> 10, within = col & 1023;
        int h = within >> 6, d = within & 63;
        float av = acc[mi][ni][r];
        size_t bh = (size_t)(b * 16 + h);
        if (which == 0)      Qb[(bh * 2048 + n) * 64 + d] = f2b(av * QSCALE);
        else if (which == 1) Kb[(bh * 2048 + n) * 64 + d] = f2b(av);
        else                 Vt[(bh * 64 + d) * 2048 + n] = f2b(av);
      }
}

// ---------------- out-proj GEMM: attnb[4096][1024] @ Wout_t[1024][1024]^T + bias ----------------
__global__ __launch_bounds__(256) void gemm_out_kernel(const u16* __restrict__ A,
                                                       const u16* __restrict__ Bt,
                                                       const float* __restrict__ bias,
                                                       float* __restrict__ out) {
  __shared__ u16 lA[128 * 32], lB[128 * 32];
  const int tid = threadIdx.x, lane = tid & 63, w = tid >> 6;
  const int wr = w >> 1, wc = w & 1, lrow = lane & 15, lk = lane >> 4;
  const int bm = blockIdx.y, bn = blockIdx.x;
  const int srow = tid >> 2, scol = (tid & 3) * 8;
  const u16* Arow = A + (size_t)(bm * 128 + srow) * 1024 + scol;
  const u16* Brow = Bt + (size_t)(bn * 128 + srow) * 1024 + scol;
  f32x4 acc[4][4] = {};
  for (int k0 = 0; k0 < 1024; k0 += 32) {
    __syncthreads();
    gload_lds16(Arow + k0,             (char*)lA + w * 1024);
    gload_lds16(Arow + 64 * 1024 + k0, (char*)lA + 4096 + w * 1024);
    gload_lds16(Brow + k0,             (char*)lB + w * 1024);
    gload_lds16(Brow + 64 * 1024 + k0, (char*)lB + 4096 + w * 1024);
    __syncthreads();
    bf16x8 af[4], bfr[4];
    for (int mi = 0; mi < 4; mi++)
      af[mi] = *(const bf16x8*)&lA[(wr * 64 + mi * 16 + lrow) * 32 + lk * 8];
    for (int ni = 0; ni < 4; ni++)
      bfr[ni] = *(const bf16x8*)&lB[(wc * 64 + ni * 16 + lrow) * 32 + lk * 8];
    for (int mi = 0; mi < 4; mi++)
      for (int ni = 0; ni < 4; ni++)
        acc[mi][ni] = __builtin_amdgcn_mfma_f32_16x16x32_bf16(af[mi], bfr[ni], acc[mi][ni], 0, 0, 0);
  }
  const int rowbase = bm * 128 + wr * 64;
  const int colbase = bn * 128 + wc * 64;
  for (int mi = 0; mi < 4; mi++)
    for (int ni = 0; ni < 4; ni++)
      for (int r = 0; r < 4; r++) {
        int row = rowbase + mi * 16 + lk * 4 + r;
        int col = colbase + ni * 16 + lrow;
        out[(size_t)row * 1024 + col] = acc[mi][ni][r] + bias[col];
      }
}

// ---------------- flash attention: swapped QK^T (32x32), LDS K/V, shfl P-repack ----
// grid (16, 32, 2), block 256 = 4 waves; wave w owns q rows [qt*128+w*32, +32);
// block z sweeps kv [z*1024, +1024) in 16 chunks of 64.
// P repack fully in-register: word p of lane (l31,hi) = kvpair (p&1)+4(p>>1)+2hi at col l31;
// consumer (kk) takes words {4kk+2hi,+1} from BOTH halves -> 2 shfl_xor(32) + cndmask per kk.
// LDS = 32KB (K/V double-buffer only) -> 4 blocks/CU; grid 1024 = 4/CU, single round.
__global__ __launch_bounds__(256, 4) void attn_kernel(const u16* __restrict__ Qb,
                                                      const u16* __restrict__ Kb,
                                                      const u16* __restrict__ Vt,
                                                      const u64* __restrict__ Mb,
                                                      u16* __restrict__ accP,
                                                      float2* __restrict__ ml) {
  __shared__ u16 Klds[2][64 * 64];  // [buf][kv][d], 128B rows, 16B-unit XOR swizzle u^=(row&7)
  __shared__ u16 Vlds[2][64 * 64];  // [buf][d][kv], same swizzle
  const int tid = threadIdx.x, lane = tid & 63, w = tid >> 6;
  const int l31 = lane & 31, hi = lane >> 5;
  const int qt = blockIdx.x, bh = blockIdx.y, z = blockIdx.z;
  const int q = qt * 128 + w * 32 + l31;
  const int kv0 = z << 10;
  const u16* Qp = Qb + (size_t)bh * 2048 * 64;
  const u16* Kp = Kb + (size_t)bh * 2048 * 64;
  const u16* Vp = Vt + (size_t)bh * 64 * 2048;
  const u64* Mrow = Mb + (size_t)q * 32;

  // staging: wave w covers rows [16w,16w+16) of both K and V^T tiles (4 instrs)
  const int rsub = lane >> 3;                       // 0..7
  const int usrc = ((lane & 7) ^ rsub) * 8;         // pre-swizzled source 16B unit
  auto stage = [&](int bi, int j0) {
#pragma unroll
    for (int j = 0; j < 2; j++) {
      const int i = w * 2 + j;                      // instr index 0..7
      const int row = 8 * i + rsub;
      gload_lds16(Kp + (size_t)(j0 + row) * 64 + usrc, (char*)&Klds[bi][0] + i * 1024);
      gload_lds16(Vp + (size_t)row * 2048 + j0 + usrc, (char*)&Vlds[bi][0] + i * 1024);
    }
  };

  // Q B-frags: col=q=lane&31, k-half by hi; resident whole kernel
  bf16x8 qf[4];
#pragma unroll
  for (int t = 0; t < 4; t++)
    qf[t] = *(const bf16x8*)&Qp[(size_t)q * 64 + t * 16 + hi * 8];

  f32x16 acc0 = {}, acc1 = {};  // O^T: d in [0,32) / [32,64), col=q
  float m_run = -3.0e38f, lsum = 0.f;

  stage(0, kv0);
  u64 mw = Mrow[kv0 >> 6];
  int cur = 0;

  for (int c = 0; c < 16; c++) {
    const int j0 = kv0 + c * 64;
    __syncthreads();  // drains vmcnt: buf[cur] staged; prior reads of buf[cur^1] done
    if (c + 1 < 16) stage(cur ^ 1, j0 + 64);
    u64 mw_n = (c + 1 < 16) ? Mrow[(j0 >> 6) + 1] : 0;

    // K frags from LDS (swizzled read)
    bf16x8 kc[2][4];
#pragma unroll
    for (int t2 = 0; t2 < 2; t2++)
#pragma unroll
      for (int t = 0; t < 4; t++) {
        const int row = t2 * 32 + l31;
        const int u = (t * 2 + hi) ^ (l31 & 7);
        kc[t2][t] = *(const bf16x8*)((const char*)&Klds[cur][0] + row * 128 + u * 16);
      }

    // S^T = K·Q^T over d=64 (log2-scaled already)
    f32x16 s0 = {}, s1 = {};
    __builtin_amdgcn_s_setprio(1);
#pragma unroll
    for (int t = 0; t < 4; t++) {
      s0 = __builtin_amdgcn_mfma_f32_32x32x16_bf16(kc[0][t], qf[t], s0, 0, 0, 0);
      s1 = __builtin_amdgcn_mfma_f32_32x32x16_bf16(kc[1][t], qf[t], s1, 0, 0, 0);
    }
    __builtin_amdgcn_s_setprio(0);

    // V frags from LDS, issued now so latency hides under softmax
    bf16x8 va[2][4];
#pragma unroll
    for (int dt = 0; dt < 2; dt++)
#pragma unroll
      for (int kk = 0; kk < 4; kk++) {
        const int row = dt * 32 + l31;
        const int u = (kk * 2 + hi) ^ (l31 & 7);
        va[dt][kk] = *(const bf16x8*)((const char*)&Vlds[cur][0] + row * 128 + u * 16);
      }

    // raw row-max (mask applied later by zeroing p; same softmax), tree + partner
    float mx[8];
#pragma unroll
    for (int i = 0; i < 8; i++)
      mx[i] = fmaxf(fmaxf(s0[i], s0[i + 8]), fmaxf(s1[i], s1[i + 8]));
    float m01 = fmaxf(mx[0], mx[1]), m23 = fmaxf(mx[2], mx[3]);
    float m45 = fmaxf(mx[4], mx[5]), m67 = fmaxf(mx[6], mx[7]);
    float pm = fmaxf(fmaxf(m01, m23), fmaxf(m45, m67));
    pm = fmaxf(pm, __shfl_xor(pm, 32, 64));

    // deferred rescale (THR=8 in log2 domain -> p bounded by 256)
    if (__any(pm > m_run + 8.f)) {
      float mn = fmaxf(m_run, pm);
      float fs = exp2_fast(m_run - mn);
      m_run = mn;
      lsum *= fs;
      acc0 *= fs;
      acc1 *= fs;
    }

    // p = exp2(s - m), mask-zero, partial sums, pack kv-pairs into u32 words in-register
    u32 w0s = (u32)(mw >> (4 * hi));          // tile0 bits, pre-shifted by 4*hi
    u32 w1s = (u32)((mw >> 32) >> (4 * hi));  // tile1 bits
    u32 w0[8], w1[8];
#pragma unroll
    for (int p = 0; p < 8; p++) {
      const int r0 = 2 * p;
      const int sh = (r0 & 3) + 8 * (p >> 1);  // kv_local - 4*hi for reg r0
      float a0 = exp2_fast(s0[r0] - m_run);
      float a1 = exp2_fast(s0[r0 + 1] - m_run);
      float b0 = exp2_fast(s1[r0] - m_run);
      float b1 = exp2_fast(s1[r0 + 1] - m_run);
      a0 = ((w0s >> sh) & 1u) ? a0 : 0.f;
      a1 = ((w0s >> (sh + 1)) & 1u) ? a1 : 0.f;
      b0 = ((w1s >> sh) & 1u) ? b0 : 0.f;
      b1 = ((w1s >> (sh + 1)) & 1u) ? b1 : 0.f;
      lsum += (a0 + a1) + (b0 + b1);
      w0[p] = (u32)f2b(a0) | ((u32)f2b(a1) << 16);
      w1[p] = (u32)f2b(b0) | ((u32)f2b(b1) << 16);
    }

    // PV: B-frags via in-register half-exchange (shfl_xor 32 preserves column l31)
    __builtin_amdgcn_s_setprio(1);
#pragma unroll
    for (int kk = 0; kk < 4; kk++) {
      const int b4 = (kk & 1) * 4;
      u32 a0w = (kk < 2) ? w0[b4 + 0] : w1[b4 + 0];
      u32 a1w = (kk < 2) ? w0[b4 + 1] : w1[b4 + 1];
      u32 a2w = (kk < 2) ? w0[b4 + 2] : w1[b4 + 2];
      u32 a3w = (kk < 2) ? w0[b4 + 3] : w1[b4 + 3];
      u32 e0 = __shfl_xor(hi ? a0w : a2w, 32, 64);
      u32 e1 = __shfl_xor(hi ? a1w : a3w, 32, 64);
      u32 f0 = hi ? e0 : a0w;
      u32 f1 = hi ? e1 : a1w;
      u32 f2c = hi ? a2w : e0;
      u32 f3 = hi ? a3w : e1;
      u32x4v pv4 = {f0, f1, f2c, f3};
      bf16x8 pbf = __builtin_bit_cast(bf16x8, pv4);
      acc0 = __builtin_amdgcn_mfma_f32_32x32x16_bf16(va[0][kk], pbf, acc0, 0, 0, 0);
      acc1 = __builtin_amdgcn_mfma_f32_32x32x16_bf16(va[1][kk], pbf, acc1, 0, 0, 0);
    }
    __builtin_amdgcn_s_setprio(0);

    mw = mw_n;
    cur ^= 1;
  }

  // partials: partner-reduce l, store raw acc (bf16) + m/l; merge kernel divides
  lsum += __shfl_xor(lsum, 32, 64);
  const size_t row = (size_t)z * 32 * 2048 + (size_t)bh * 2048 + q;
  u16* ap = accP + row * 64;
#pragma unroll
  for (int rq = 0; rq < 4; rq++) {
    const int rb = rq * 4;
    {
      u32 lo = (u32)f2b(acc0[rb]) | ((u32)f2b(acc0[rb + 1]) << 16);
      u32 hi2 = (u32)f2b(acc0[rb + 2]) | ((u32)f2b(acc0[rb + 3]) << 16);
      uint2 st; st.x = lo; st.y = hi2;
      *(uint2*)(ap + 8 * rq + 4 * hi) = st;
    }
    {
      u32 lo = (u32)f2b(acc1[rb]) | ((u32)f2b(acc1[rb + 1]) << 16);
      u32 hi2 = (u32)f2b(acc1[rb + 2]) | ((u32)f2b(acc1[rb + 3]) << 16);
      uint2 st; st.x = lo; st.y = hi2;
      *(uint2*)(ap + 32 + 8 * rq + 4 * hi) = st;
    }
  }
  if (hi == 0) ml[row] = make_float2(m_run, lsum);
}

// ---------------- merge the two KV-half partials (exact rescale-add) ----------------
// 1M threads: gid>>4 = row (bh*2048+q), gid&15 = d-quad. Fully coalesced.
__global__ __launch_bounds__(256) void attn_merge_kernel(const u16* __restrict__ accP,
                                                         const float2* __restrict__ ml,
                                                         u16* __restrict__ attnb) {
  const int gid = blockIdx.x * 256 + threadIdx.x;
  const int row = gid >> 4;
  const int dq = gid & 15;
  const size_t Z = (size_t)32 * 2048;
  float2 mlA = ml[row], mlB = ml[Z + row];
  float mT = fmaxf(mlA.x, mlB.x);
  float fA = exp2_fast(mlA.x - mT), fB = exp2_fast(mlB.x - mT);
  float inv = 1.0f / (mlA.y * fA + mlB.y * fB);
  fA *= inv; fB *= inv;
  const u16* pA = accP + (size_t)row * 64 + dq * 4;
  const u16* pB = pA + Z * 64;
  ushort4 a = *(const ushort4*)pA, bv = *(const ushort4*)pB;
  ushort4 o;
  o.x = f2b(b2f(a.x) * fA + b2f(bv.x) * fB);
  o.y = f2b(b2f(a.y) * fA + b2f(bv.y) * fB);
  o.z = f2b(b2f(a.z) * fA + b2f(bv.z) * fB);
  o.w = f2b(b2f(a.w) * fA + b2f(bv.w) * fB);
  const int bh = row >> 11, q = row & 2047, b = bh >> 4, h = bh & 15;
  *(ushort4*)(attnb + ((size_t)b * 2048 + q) * 1024 + h * 64 + dq * 4) = o;
}

extern "C" void kernel_launch(void* const* d_in, const int* in_sizes, int n_in,
                              void* d_out, int out_size, void* d_ws, size_t ws_size,
                              hipStream_t stream) {
  const float* x    = (const float*)d_in[0];
  const int*   mask = (const int*)d_in[1];
  const float* Wqkv = (const float*)d_in[2];
  const float* Wout = (const float*)d_in[3];
  const float* bout = (const float*)d_in[4];
  float* out = (float*)d_out;

  char* ws = (char*)d_ws;
  // layout (bytes): [0,8M) xb / attnb; [8,14M) Wqkv_t -> [8,10M) Wout_t + [10,10.5M) mbits;
  // [14,22M) Qb; [22,30M) Kb; [30,38M) Vt; [38M,54.8M) accP (bf16, z-major); [55M,56M) ml
  u16* xb     = (u16*)(ws);
  u16* attnb  = xb;
  u16* Wqkv_t = (u16*)(ws + (size_t)(8u << 20));
  u16* Wout_t = Wqkv_t;
  u64* mbits  = (u64*)(ws + (size_t)(10u << 20));
  u16* Qb     = (u16*)(ws + (size_t)(14u << 20));
  u16* Kb     = (u16*)(ws + (size_t)(22u << 20));
  u16* Vt     = (u16*)(ws + (size_t)(30u << 20));
  u16* accP   = (u16*)(ws + (size_t)(38u << 20));
  float2* ml  = (float2*)(ws + (size_t)(55u << 20));

  cast_bf16_kernel<<<4096, 256, 0, stream>>>(x, xb, 4096 * 1024 / 4);
  transpose_cast_kernel<<<dim3(96, 32), dim3(32, 8), 0, stream>>>(Wqkv, Wqkv_t, 1024, 3072);
  gemm_qkv_kernel<<<dim3(24, 32), 256, 0, stream>>>(xb, Wqkv_t, Qb, Kb, Vt);
  transpose_cast_kernel<<<dim3(32, 32), dim3(32, 8), 0, stream>>>(Wout, Wout_t, 1024, 1024);
  maskbits_kernel<<<16384, 256, 0, stream>>>(mask, mbits);
  attn_kernel<<<dim3(16, 32, 2), 256, 0, stream>>>(Qb, Kb, Vt, mbits, accP, ml);
  attn_merge_kernel<<<4096, 256, 0, stream>>>(accP, ml, attnb);
  gemm_out_kernel<<<dim3(8, 32), 256, 0, stream>>>(attnb, Wout_t, bout, out);
}

// Round 10
// 169.398 us; speedup vs baseline: 1.1443x; 1.1443x over previous
//
#include <hip/hip_runtime.h>
#include <hip/hip_bf16.h>

typedef __bf16 bf16x8 __attribute__((ext_vector_type(8)));
typedef float f32x4 __attribute__((ext_vector_type(4)));
typedef float f32x16 __attribute__((ext_vector_type(16)));
typedef unsigned short u16;
typedef unsigned int u32;
typedef unsigned long long u64;
typedef u32 u32x4v __attribute__((ext_vector_type(4)));

#define QSCALE 0.18033688011112042f  /* log2(e)/8 : folds SCALE and exp->exp2 into Q */

__device__ __forceinline__ u16 f2b(float x) {
  __hip_bfloat16 h = __float2bfloat16(x);
  return __builtin_bit_cast(u16, h);
}

__device__ __forceinline__ float b2f(u16 x) {
  u32 u = ((u32)x) << 16;
  return __builtin_bit_cast(float, u);
}

__device__ __forceinline__ float exp2_fast(float x) {
#if __has_builtin(__builtin_amdgcn_exp2f)
  return __builtin_amdgcn_exp2f(x);
#else
  float r; asm("v_exp_f32 %0, %1" : "=v"(r) : "v"(x)); return r;
#endif
}

// async global->LDS, 16B per lane; LDS dest = wave-uniform base + lane*16
__device__ __forceinline__ void gload_lds16(const void* g, void* l) {
  __builtin_amdgcn_global_load_lds((const __attribute__((address_space(1))) u32*)g,
                                   (__attribute__((address_space(3))) u32*)l, 16, 0, 0);
}

// ---------------- cast f32 -> bf16 (4 elems/thread) ----------------
__global__ __launch_bounds__(256) void cast_bf16_kernel(const float* __restrict__ src,
                                                        u16* __restrict__ dst, int n4) {
  int i = blockIdx.x * 256 + threadIdx.x;
  if (i >= n4) return;
  float4 v = ((const float4*)src)[i];
  ushort4 o;
  o.x = f2b(v.x); o.y = f2b(v.y); o.z = f2b(v.z); o.w = f2b(v.w);
  ((ushort4*)dst)[i] = o;
}

// ---------------- transpose+cast: src [R][C] f32 -> dst [C][R] bf16 ----------------
__global__ __launch_bounds__(256) void transpose_cast_kernel(const float* __restrict__ src,
                                                             u16* __restrict__ dst,
                                                             int R, int C) {
  __shared__ float t[32][33];
  int c0 = blockIdx.x * 32, r0 = blockIdx.y * 32;
  int tx = threadIdx.x, ty = threadIdx.y;
  for (int k = 0; k < 32; k += 8)
    t[ty + k][tx] = src[(size_t)(r0 + ty + k) * C + c0 + tx];
  __syncthreads();
  for (int k = 0; k < 32; k += 8)
    dst[(size_t)(c0 + ty + k) * R + r0 + tx] = f2b(t[tx][ty + k]);
}

// ---------------- mask [2048][2048] int32 -> bit-packed u64 words ----------------
__global__ __launch_bounds__(256) void maskbits_kernel(const int* __restrict__ mask,
                                                       u64* __restrict__ bits) {
  int gtid = blockIdx.x * 256 + threadIdx.x;
  int wid = gtid >> 6, lane = gtid & 63;
  int v = mask[(size_t)wid * 64 + lane];
  u64 b = __ballot(v != 0);
  if (lane == 0) bits[wid] = b;
}

// ---------------- QKV GEMM: xb[4096][1024] @ Wqkv_t[3072][1024]^T ----------------
// m97 structure: global_load_lds(16B) staging, 2 barriers per K-step.
// Epilogue scatters into Qb (pre-scaled by QSCALE) / Kb [B][H][N][64], Vt [B][H][64][N].
__global__ __launch_bounds__(256) void gemm_qkv_kernel(const u16* __restrict__ A,
                                                       const u16* __restrict__ Bt,
                                                       u16* __restrict__ Qb,
                                                       u16* __restrict__ Kb,
                                                       u16* __restrict__ Vt) {
  __shared__ u16 lA[128 * 32], lB[128 * 32];
  const int tid = threadIdx.x, lane = tid & 63, w = tid >> 6;
  const int wr = w >> 1, wc = w & 1, lrow = lane & 15, lk = lane >> 4;
  const int bm = blockIdx.y, bn = blockIdx.x;
  const int srow = tid >> 2, scol = (tid & 3) * 8;
  const u16* Arow = A + (size_t)(bm * 128 + srow) * 1024 + scol;
  const u16* Brow = Bt + (size_t)(bn * 128 + srow) * 1024 + scol;
  f32x4 acc[4][4] = {};
  for (int k0 = 0; k0 < 1024; k0 += 32) {
    __syncthreads();  // prior iteration's ds_reads done before overwrite
    gload_lds16(Arow + k0,             (char*)lA + w * 1024);
    gload_lds16(Arow + 64 * 1024 + k0, (char*)lA + 4096 + w * 1024);
    gload_lds16(Brow + k0,             (char*)lB + w * 1024);
    gload_lds16(Brow + 64 * 1024 + k0, (char*)lB + 4096 + w * 1024);
    __syncthreads();  // drains vmcnt: staged data visible
    bf16x8 af[4], bfr[4];
    for (int mi = 0; mi < 4; mi++)
      af[mi] = *(const bf16x8*)&lA[(wr * 64 + mi * 16 + lrow) * 32 + lk * 8];
    for (int ni = 0; ni < 4; ni++)
      bfr[ni] = *(const bf16x8*)&lB[(wc * 64 + ni * 16 + lrow) * 32 + lk * 8];
    for (int mi = 0; mi < 4; mi++)
      for (int ni = 0; ni < 4; ni++)
        acc[mi][ni] = __builtin_amdgcn_mfma_f32_16x16x32_bf16(af[mi], bfr[ni], acc[mi][ni], 0, 0, 0);
  }
  const int rowbase = bm * 128 + wr * 64;
  const int colbase = bn * 128 + wc * 64;
  for (int mi = 0; mi < 4; mi++)
    for (int ni = 0; ni < 4; ni++)
      for (int r = 0; r < 4; r++) {
        int row = rowbase + mi * 16 + lk * 4 + r;
        int col = colbase + ni * 16 + lrow;
        int b = row >> 11, n = row & 2047;
        int which = col >> 10, within = col & 1023;
        int h = within >> 6, d = within & 63;
        float av = acc[mi][ni][r];
        size_t bh = (size_t)(b * 16 + h);
        if (which == 0)      Qb[(bh * 2048 + n) * 64 + d] = f2b(av * QSCALE);
        else if (which == 1) Kb[(bh * 2048 + n) * 64 + d] = f2b(av);
        else                 Vt[(bh * 64 + d) * 2048 + n] = f2b(av);
      }
}

// ---------------- out-proj GEMM: attnb[4096][1024] @ Wout_t[1024][1024]^T + bias ----------------
__global__ __launch_bounds__(256) void gemm_out_kernel(const u16* __restrict__ A,
                                                       const u16* __restrict__ Bt,
                                                       const float* __restrict__ bias,
                                                       float* __restrict__ out) {
  __shared__ u16 lA[128 * 32], lB[128 * 32];
  const int tid = threadIdx.x, lane = tid & 63, w = tid >> 6;
  const int wr = w >> 1, wc = w & 1, lrow = lane & 15, lk = lane >> 4;
  const int bm = blockIdx.y, bn = blockIdx.x;
  const int srow = tid >> 2, scol = (tid & 3) * 8;
  const u16* Arow = A + (size_t)(bm * 128 + srow) * 1024 + scol;
  const u16* Brow = Bt + (size_t)(bn * 128 + srow) * 1024 + scol;
  f32x4 acc[4][4] = {};
  for (int k0 = 0; k0 < 1024; k0 += 32) {
    __syncthreads();
    gload_lds16(Arow + k0,             (char*)lA + w * 1024);
    gload_lds16(Arow + 64 * 1024 + k0, (char*)lA + 4096 + w * 1024);
    gload_lds16(Brow + k0,             (char*)lB + w * 1024);
    gload_lds16(Brow + 64 * 1024 + k0, (char*)lB + 4096 + w * 1024);
    __syncthreads();
    bf16x8 af[4], bfr[4];
    for (int mi = 0; mi < 4; mi++)
      af[mi] = *(const bf16x8*)&lA[(wr * 64 + mi * 16 + lrow) * 32 + lk * 8];
    for (int ni = 0; ni < 4; ni++)
      bfr[ni] = *(const bf16x8*)&lB[(wc * 64 + ni * 16 + lrow) * 32 + lk * 8];
    for (int mi = 0; mi < 4; mi++)
      for (int ni = 0; ni < 4; ni++)
        acc[mi][ni] = __builtin_amdgcn_mfma_f32_16x16x32_bf16(af[mi], bfr[ni], acc[mi][ni], 0, 0, 0);
  }
  const int rowbase = bm * 128 + wr * 64;
  const int colbase = bn * 128 + wc * 64;
  for (int mi = 0; mi < 4; mi++)
    for (int ni = 0; ni < 4; ni++)
      for (int r = 0; r < 4; r++) {
        int row = rowbase + mi * 16 + lk * 4 + r;
        int col = colbase + ni * 16 + lrow;
        out[(size_t)row * 1024 + col] = acc[mi][ni][r] + bias[col];
      }
}

// ---------------- flash attention: swapped QK^T (32x32), LDS K/V, shfl P-repack ----
// grid (16, 32, 2), block 256 = 4 waves; wave w owns q rows [qt*128+w*32, +32);
// block z sweeps kv [z*1024, +1024) in 16 chunks of 64.
// P repack fully in-register (shfl_xor 32 half-exchange; validated r9 pass).
// __launch_bounds__ 2nd arg: empirical VGPR cap = 256/arg2 on this toolchain
// ((512,4)->64, (512,2)->128, (256,3)->80, (256,4)->64 spilled). arg2=2 -> cap 128.
// LDS 32KB -> 5 blocks/CU by LDS; VGPR@4waves/SIMD -> 4 blocks/CU; grid 1024 = one round.
__global__ __launch_bounds__(256, 2) void attn_kernel(const u16* __restrict__ Qb,
                                                      const u16* __restrict__ Kb,
                                                      const u16* __restrict__ Vt,
                                                      const u64* __restrict__ Mb,
                                                      u16* __restrict__ accP,
                                                      float2* __restrict__ ml) {
  __shared__ u16 Klds[2][64 * 64];  // [buf][kv][d], 128B rows, 16B-unit XOR swizzle u^=(row&7)
  __shared__ u16 Vlds[2][64 * 64];  // [buf][d][kv], same swizzle
  const int tid = threadIdx.x, lane = tid & 63, w = tid >> 6;
  const int l31 = lane & 31, hi = lane >> 5;
  const int qt = blockIdx.x, bh = blockIdx.y, z = blockIdx.z;
  const int q = qt * 128 + w * 32 + l31;
  const int kv0 = z << 10;
  const u16* Qp = Qb + (size_t)bh * 2048 * 64;
  const u16* Kp = Kb + (size_t)bh * 2048 * 64;
  const u16* Vp = Vt + (size_t)bh * 64 * 2048;
  const u64* Mrow = Mb + (size_t)q * 32;

  // staging: wave w covers rows [16w,16w+16) of both K and V^T tiles (4 instrs)
  const int rsub = lane >> 3;                       // 0..7
  const int usrc = ((lane & 7) ^ rsub) * 8;         // pre-swizzled source 16B unit
  auto stage = [&](int bi, int j0) {
#pragma unroll
    for (int j = 0; j < 2; j++) {
      const int i = w * 2 + j;                      // instr index 0..7
      const int row = 8 * i + rsub;
      gload_lds16(Kp + (size_t)(j0 + row) * 64 + usrc, (char*)&Klds[bi][0] + i * 1024);
      gload_lds16(Vp + (size_t)row * 2048 + j0 + usrc, (char*)&Vlds[bi][0] + i * 1024);
    }
  };

  // Q B-frags: col=q=lane&31, k-half by hi; resident whole kernel
  bf16x8 qf[4];
#pragma unroll
  for (int t = 0; t < 4; t++)
    qf[t] = *(const bf16x8*)&Qp[(size_t)q * 64 + t * 16 + hi * 8];

  f32x16 acc0 = {}, acc1 = {};  // O^T: d in [0,32) / [32,64), col=q
  float m_run = -3.0e38f, lsum = 0.f;

  stage(0, kv0);
  u64 mw = Mrow[kv0 >> 6];
  int cur = 0;

  for (int c = 0; c < 16; c++) {
    const int j0 = kv0 + c * 64;
    __syncthreads();  // drains vmcnt: buf[cur] staged; prior reads of buf[cur^1] done
    if (c + 1 < 16) stage(cur ^ 1, j0 + 64);
    u64 mw_n = (c + 1 < 16) ? Mrow[(j0 >> 6) + 1] : 0;

    // K frags from LDS (swizzled read)
    bf16x8 kc[2][4];
#pragma unroll
    for (int t2 = 0; t2 < 2; t2++)
#pragma unroll
      for (int t = 0; t < 4; t++) {
        const int row = t2 * 32 + l31;
        const int u = (t * 2 + hi) ^ (l31 & 7);
        kc[t2][t] = *(const bf16x8*)((const char*)&Klds[cur][0] + row * 128 + u * 16);
      }

    // S^T = K·Q^T over d=64 (log2-scaled already)
    f32x16 s0 = {}, s1 = {};
    __builtin_amdgcn_s_setprio(1);
#pragma unroll
    for (int t = 0; t < 4; t++) {
      s0 = __builtin_amdgcn_mfma_f32_32x32x16_bf16(kc[0][t], qf[t], s0, 0, 0, 0);
      s1 = __builtin_amdgcn_mfma_f32_32x32x16_bf16(kc[1][t], qf[t], s1, 0, 0, 0);
    }
    __builtin_amdgcn_s_setprio(0);

    // V frags from LDS, issued now so latency hides under softmax
    bf16x8 va[2][4];
#pragma unroll
    for (int dt = 0; dt < 2; dt++)
#pragma unroll
      for (int kk = 0; kk < 4; kk++) {
        const int row = dt * 32 + l31;
        const int u = (kk * 2 + hi) ^ (l31 & 7);
        va[dt][kk] = *(const bf16x8*)((const char*)&Vlds[cur][0] + row * 128 + u * 16);
      }

    // raw row-max (mask applied later by zeroing p; same softmax), tree + partner
    float mx[8];
#pragma unroll
    for (int i = 0; i < 8; i++)
      mx[i] = fmaxf(fmaxf(s0[i], s0[i + 8]), fmaxf(s1[i], s1[i + 8]));
    float m01 = fmaxf(mx[0], mx[1]), m23 = fmaxf(mx[2], mx[3]);
    float m45 = fmaxf(mx[4], mx[5]), m67 = fmaxf(mx[6], mx[7]);
    float pm = fmaxf(fmaxf(m01, m23), fmaxf(m45, m67));
    pm = fmaxf(pm, __shfl_xor(pm, 32, 64));

    // deferred rescale (THR=8 in log2 domain -> p bounded by 256)
    if (__any(pm > m_run + 8.f)) {
      float mn = fmaxf(m_run, pm);
      float fs = exp2_fast(m_run - mn);
      m_run = mn;
      lsum *= fs;
      acc0 *= fs;
      acc1 *= fs;
    }

    // p = exp2(s - m), mask-zero, partial sums, pack kv-pairs into u32 words in-register
    u32 w0s = (u32)(mw >> (4 * hi));          // tile0 bits, pre-shifted by 4*hi
    u32 w1s = (u32)((mw >> 32) >> (4 * hi));  // tile1 bits
    u32 w0[8], w1[8];
#pragma unroll
    for (int p = 0; p < 8; p++) {
      const int r0 = 2 * p;
      const int sh = (r0 & 3) + 8 * (p >> 1);  // kv_local - 4*hi for reg r0
      float a0 = exp2_fast(s0[r0] - m_run);
      float a1 = exp2_fast(s0[r0 + 1] - m_run);
      float b0 = exp2_fast(s1[r0] - m_run);
      float b1 = exp2_fast(s1[r0 + 1] - m_run);
      a0 = ((w0s >> sh) & 1u) ? a0 : 0.f;
      a1 = ((w0s >> (sh + 1)) & 1u) ? a1 : 0.f;
      b0 = ((w1s >> sh) & 1u) ? b0 : 0.f;
      b1 = ((w1s >> (sh + 1)) & 1u) ? b1 : 0.f;
      lsum += (a0 + a1) + (b0 + b1);
      w0[p] = (u32)f2b(a0) | ((u32)f2b(a1) << 16);
      w1[p] = (u32)f2b(b0) | ((u32)f2b(b1) << 16);
    }

    // PV: B-frags via in-register half-exchange (shfl_xor 32 preserves column l31)
    __builtin_amdgcn_s_setprio(1);
#pragma unroll
    for (int kk = 0; kk < 4; kk++) {
      const int b4 = (kk & 1) * 4;
      u32 a0w = (kk < 2) ? w0[b4 + 0] : w1[b4 + 0];
      u32 a1w = (kk < 2) ? w0[b4 + 1] : w1[b4 + 1];
      u32 a2w = (kk < 2) ? w0[b4 + 2] : w1[b4 + 2];
      u32 a3w = (kk < 2) ? w0[b4 + 3] : w1[b4 + 3];
      u32 e0 = __shfl_xor(hi ? a0w : a2w, 32, 64);
      u32 e1 = __shfl_xor(hi ? a1w : a3w, 32, 64);
      u32 f0 = hi ? e0 : a0w;
      u32 f1 = hi ? e1 : a1w;
      u32 f2c = hi ? a2w : e0;
      u32 f3 = hi ? a3w : e1;
      u32x4v pv4 = {f0, f1, f2c, f3};
      bf16x8 pbf = __builtin_bit_cast(bf16x8, pv4);
      acc0 = __builtin_amdgcn_mfma_f32_32x32x16_bf16(va[0][kk], pbf, acc0, 0, 0, 0);
      acc1 = __builtin_amdgcn_mfma_f32_32x32x16_bf16(va[1][kk], pbf, acc1, 0, 0, 0);
    }
    __builtin_amdgcn_s_setprio(0);

    mw = mw_n;
    cur ^= 1;
  }

  // partials: partner-reduce l, store raw acc (bf16) + m/l; merge kernel divides
  lsum += __shfl_xor(lsum, 32, 64);
  const size_t row = (size_t)z * 32 * 2048 + (size_t)bh * 2048 + q;
  u16* ap = accP + row * 64;
#pragma unroll
  for (int rq = 0; rq < 4; rq++) {
    const int rb = rq * 4;
    {
      u32 lo = (u32)f2b(acc0[rb]) | ((u32)f2b(acc0[rb + 1]) << 16);
      u32 hi2 = (u32)f2b(acc0[rb + 2]) | ((u32)f2b(acc0[rb + 3]) << 16);
      uint2 st; st.x = lo; st.y = hi2;
      *(uint2*)(ap + 8 * rq + 4 * hi) = st;
    }
    {
      u32 lo = (u32)f2b(acc1[rb]) | ((u32)f2b(acc1[rb + 1]) << 16);
      u32 hi2 = (u32)f2b(acc1[rb + 2]) | ((u32)f2b(acc1[rb + 3]) << 16);
      uint2 st; st.x = lo; st.y = hi2;
      *(uint2*)(ap + 32 + 8 * rq + 4 * hi) = st;
    }
  }
  if (hi == 0) ml[row] = make_float2(m_run, lsum);
}

// ---------------- merge the two KV-half partials (exact rescale-add) ----------------
// 1M threads: gid>>4 = row (bh*2048+q), gid&15 = d-quad. Fully coalesced.
__global__ __launch_bounds__(256) void attn_merge_kernel(const u16* __restrict__ accP,
                                                         const float2* __restrict__ ml,
                                                         u16* __restrict__ attnb) {
  const int gid = blockIdx.x * 256 + threadIdx.x;
  const int row = gid >> 4;
  const int dq = gid & 15;
  const size_t Z = (size_t)32 * 2048;
  float2 mlA = ml[row], mlB = ml[Z + row];
  float mT = fmaxf(mlA.x, mlB.x);
  float fA = exp2_fast(mlA.x - mT), fB = exp2_fast(mlB.x - mT);
  float inv = 1.0f / (mlA.y * fA + mlB.y * fB);
  fA *= inv; fB *= inv;
  const u16* pA = accP + (size_t)row * 64 + dq * 4;
  const u16* pB = pA + Z * 64;
  ushort4 a = *(const ushort4*)pA, bv = *(const ushort4*)pB;
  ushort4 o;
  o.x = f2b(b2f(a.x) * fA + b2f(bv.x) * fB);
  o.y = f2b(b2f(a.y) * fA + b2f(bv.y) * fB);
  o.z = f2b(b2f(a.z) * fA + b2f(bv.z) * fB);
  o.w = f2b(b2f(a.w) * fA + b2f(bv.w) * fB);
  const int bh = row >> 11, q = row & 2047, b = bh >> 4, h = bh & 15;
  *(ushort4*)(attnb + ((size_t)b * 2048 + q) * 1024 + h * 64 + dq * 4) = o;
}

extern "C" void kernel_launch(void* const* d_in, const int* in_sizes, int n_in,
                              void* d_out, int out_size, void* d_ws, size_t ws_size,
                              hipStream_t stream) {
  const float* x    = (const float*)d_in[0];
  const int*   mask = (const int*)d_in[1];
  const float* Wqkv = (const float*)d_in[2];
  const float* Wout = (const float*)d_in[3];
  const float* bout = (const float*)d_in[4];
  float* out = (float*)d_out;

  char* ws = (char*)d_ws;
  // layout (bytes): [0,8M) xb / attnb; [8,14M) Wqkv_t -> [8,10M) Wout_t + [10,10.5M) mbits;
  // [14,22M) Qb; [22,30M) Kb; [30,38M) Vt; [38M,54.8M) accP (bf16, z-major); [55M,56M) ml
  u16* xb     = (u16*)(ws);
  u16* attnb  = xb;
  u16* Wqkv_t = (u16*)(ws + (size_t)(8u << 20));
  u16* Wout_t = Wqkv_t;
  u64* mbits  = (u64*)(ws + (size_t)(10u << 20));
  u16* Qb     = (u16*)(ws + (size_t)(14u << 20));
  u16* Kb     = (u16*)(ws + (size_t)(22u << 20));
  u16* Vt     = (u16*)(ws + (size_t)(30u << 20));
  u16* accP   = (u16*)(ws + (size_t)(38u << 20));
  float2* ml  = (float2*)(ws + (size_t)(55u << 20));

  cast_bf16_kernel<<<4096, 256, 0, stream>>>(x, xb, 4096 * 1024 / 4);
  transpose_cast_kernel<<<dim3(96, 32), dim3(32, 8), 0, stream>>>(Wqkv, Wqkv_t, 1024, 3072);
  gemm_qkv_kernel<<<dim3(24, 32), 256, 0, stream>>>(xb, Wqkv_t, Qb, Kb, Vt);
  transpose_cast_kernel<<<dim3(32, 32), dim3(32, 8), 0, stream>>>(Wout, Wout_t, 1024, 1024);
  maskbits_kernel<<<16384, 256, 0, stream>>>(mask, mbits);
  attn_kernel<<<dim3(16, 32, 2), 256, 0, stream>>>(Qb, Kb, Vt, mbits, accP, ml);
  attn_merge_kernel<<<4096, 256, 0, stream>>>(accP, ml, attnb);
  gemm_out_kernel<<<dim3(8, 32), 256, 0, stream>>>(attnb, Wout_t, bout, out);
}

// Round 11
// 159.396 us; speedup vs baseline: 1.2161x; 1.0627x over previous
//
#include <hip/hip_runtime.h>
#include <hip/hip_bf16.h>

typedef __bf16 bf16x8 __attribute__((ext_vector_type(8)));
typedef float f32x4 __attribute__((ext_vector_type(4)));
typedef float f32x16 __attribute__((ext_vector_type(16)));
typedef unsigned short u16;
typedef unsigned int u32;
typedef unsigned long long u64;
typedef u32 u32x4v __attribute__((ext_vector_type(4)));

#define QSCALE 0.18033688011112042f  /* log2(e)/8 : folds SCALE and exp->exp2 into Q */

__device__ __forceinline__ u16 f2b(float x) {
  __hip_bfloat16 h = __float2bfloat16(x);
  return __builtin_bit_cast(u16, h);
}

__device__ __forceinline__ float exp2_fast(float x) {
#if __has_builtin(__builtin_amdgcn_exp2f)
  return __builtin_amdgcn_exp2f(x);
#else
  float r; asm("v_exp_f32 %0, %1" : "=v"(r) : "v"(x)); return r;
#endif
}

// async global->LDS, 16B per lane; LDS dest = wave-uniform base + lane*16
__device__ __forceinline__ void gload_lds16(const void* g, void* l) {
  __builtin_amdgcn_global_load_lds((const __attribute__((address_space(1))) u32*)g,
                                   (__attribute__((address_space(3))) u32*)l, 16, 0, 0);
}

// ---------------- cast f32 -> bf16 (4 elems/thread) ----------------
__global__ __launch_bounds__(256) void cast_bf16_kernel(const float* __restrict__ src,
                                                        u16* __restrict__ dst, int n4) {
  int i = blockIdx.x * 256 + threadIdx.x;
  if (i >= n4) return;
  float4 v = ((const float4*)src)[i];
  ushort4 o;
  o.x = f2b(v.x); o.y = f2b(v.y); o.z = f2b(v.z); o.w = f2b(v.w);
  ((ushort4*)dst)[i] = o;
}

// ---------------- transpose+cast: src [R][C] f32 -> dst [C][R] bf16 ----------------
__global__ __launch_bounds__(256) void transpose_cast_kernel(const float* __restrict__ src,
                                                             u16* __restrict__ dst,
                                                             int R, int C) {
  __shared__ float t[32][33];
  int c0 = blockIdx.x * 32, r0 = blockIdx.y * 32;
  int tx = threadIdx.x, ty = threadIdx.y;
  for (int k = 0; k < 32; k += 8)
    t[ty + k][tx] = src[(size_t)(r0 + ty + k) * C + c0 + tx];
  __syncthreads();
  for (int k = 0; k < 32; k += 8)
    dst[(size_t)(c0 + ty + k) * R + r0 + tx] = f2b(t[tx][ty + k]);
}

// ---------------- mask [2048][2048] int32 -> bit-packed u64 words ----------------
__global__ __launch_bounds__(256) void maskbits_kernel(const int* __restrict__ mask,
                                                       u64* __restrict__ bits) {
  int gtid = blockIdx.x * 256 + threadIdx.x;
  int wid = gtid >> 6, lane = gtid & 63;
  int v = mask[(size_t)wid * 64 + lane];
  u64 b = __ballot(v != 0);
  if (lane == 0) bits[wid] = b;
}

// ---------------- QKV GEMM: xb[4096][1024] @ Wqkv_t[3072][1024]^T ----------------
// m97 structure: global_load_lds(16B) staging, 2 barriers per K-step.
// Epilogue scatters into Qb (pre-scaled by QSCALE) / Kb [B][H][N][64], Vt [B][H][64][N].
__global__ __launch_bounds__(256) void gemm_qkv_kernel(const u16* __restrict__ A,
                                                       const u16* __restrict__ Bt,
                                                       u16* __restrict__ Qb,
                                                       u16* __restrict__ Kb,
                                                       u16* __restrict__ Vt) {
  __shared__ u16 lA[128 * 32], lB[128 * 32];
  const int tid = threadIdx.x, lane = tid & 63, w = tid >> 6;
  const int wr = w >> 1, wc = w & 1, lrow = lane & 15, lk = lane >> 4;
  const int bm = blockIdx.y, bn = blockIdx.x;
  const int srow = tid >> 2, scol = (tid & 3) * 8;
  const u16* Arow = A + (size_t)(bm * 128 + srow) * 1024 + scol;
  const u16* Brow = Bt + (size_t)(bn * 128 + srow) * 1024 + scol;
  f32x4 acc[4][4] = {};
  for (int k0 = 0; k0 < 1024; k0 += 32) {
    __syncthreads();  // prior iteration's ds_reads done before overwrite
    gload_lds16(Arow + k0,             (char*)lA + w * 1024);
    gload_lds16(Arow + 64 * 1024 + k0, (char*)lA + 4096 + w * 1024);
    gload_lds16(Brow + k0,             (char*)lB + w * 1024);
    gload_lds16(Brow + 64 * 1024 + k0, (char*)lB + 4096 + w * 1024);
    __syncthreads();  // drains vmcnt: staged data visible
    bf16x8 af[4], bfr[4];
    for (int mi = 0; mi < 4; mi++)
      af[mi] = *(const bf16x8*)&lA[(wr * 64 + mi * 16 + lrow) * 32 + lk * 8];
    for (int ni = 0; ni < 4; ni++)
      bfr[ni] = *(const bf16x8*)&lB[(wc * 64 + ni * 16 + lrow) * 32 + lk * 8];
    for (int mi = 0; mi < 4; mi++)
      for (int ni = 0; ni < 4; ni++)
        acc[mi][ni] = __builtin_amdgcn_mfma_f32_16x16x32_bf16(af[mi], bfr[ni], acc[mi][ni], 0, 0, 0);
  }
  const int rowbase = bm * 128 + wr * 64;
  const int colbase = bn * 128 + wc * 64;
  for (int mi = 0; mi < 4; mi++)
    for (int ni = 0; ni < 4; ni++)
      for (int r = 0; r < 4; r++) {
        int row = rowbase + mi * 16 + lk * 4 + r;
        int col = colbase + ni * 16 + lrow;
        int b = row >> 11, n = row & 2047;
        int which = col >> 10, within = col & 1023;
        int h = within >> 6, d = within & 63;
        float av = acc[mi][ni][r];
        size_t bh = (size_t)(b * 16 + h);
        if (which == 0)      Qb[(bh * 2048 + n) * 64 + d] = f2b(av * QSCALE);
        else if (which == 1) Kb[(bh * 2048 + n) * 64 + d] = f2b(av);
        else                 Vt[(bh * 64 + d) * 2048 + n] = f2b(av);
      }
}

// ---------------- out-proj GEMM: attnb[4096][1024] @ Wout_t[1024][1024]^T + bias ----------------
__global__ __launch_bounds__(256) void gemm_out_kernel(const u16* __restrict__ A,
                                                       const u16* __restrict__ Bt,
                                                       const float* __restrict__ bias,
                                                       float* __restrict__ out) {
  __shared__ u16 lA[128 * 32], lB[128 * 32];
  const int tid = threadIdx.x, lane = tid & 63, w = tid >> 6;
  const int wr = w >> 1, wc = w & 1, lrow = lane & 15, lk = lane >> 4;
  const int bm = blockIdx.y, bn = blockIdx.x;
  const int srow = tid >> 2, scol = (tid & 3) * 8;
  const u16* Arow = A + (size_t)(bm * 128 + srow) * 1024 + scol;
  const u16* Brow = Bt + (size_t)(bn * 128 + srow) * 1024 + scol;
  f32x4 acc[4][4] = {};
  for (int k0 = 0; k0 < 1024; k0 += 32) {
    __syncthreads();
    gload_lds16(Arow + k0,             (char*)lA + w * 1024);
    gload_lds16(Arow + 64 * 1024 + k0, (char*)lA + 4096 + w * 1024);
    gload_lds16(Brow + k0,             (char*)lB + w * 1024);
    gload_lds16(Brow + 64 * 1024 + k0, (char*)lB + 4096 + w * 1024);
    __syncthreads();
    bf16x8 af[4], bfr[4];
    for (int mi = 0; mi < 4; mi++)
      af[mi] = *(const bf16x8*)&lA[(wr * 64 + mi * 16 + lrow) * 32 + lk * 8];
    for (int ni = 0; ni < 4; ni++)
      bfr[ni] = *(const bf16x8*)&lB[(wc * 64 + ni * 16 + lrow) * 32 + lk * 8];
    for (int mi = 0; mi < 4; mi++)
      for (int ni = 0; ni < 4; ni++)
        acc[mi][ni] = __builtin_amdgcn_mfma_f32_16x16x32_bf16(af[mi], bfr[ni], acc[mi][ni], 0, 0, 0);
  }
  const int rowbase = bm * 128 + wr * 64;
  const int colbase = bn * 128 + wc * 64;
  for (int mi = 0; mi < 4; mi++)
    for (int ni = 0; ni < 4; ni++)
      for (int r = 0; r < 4; r++) {
        int row = rowbase + mi * 16 + lk * 4 + r;
        int col = colbase + ni * 16 + lrow;
        out[(size_t)row * 1024 + col] = acc[mi][ni][r] + bias[col];
      }
}

// ---------------- flash attention: swapped QK^T (32x32), kv-half wave split ----
// grid (32, 32), block 256 = 4 waves: wave = (wq = w&1 q-tile, wk = w>>1 kv-half).
// Block covers 64 q-rows, sweeps all 2048 kv in 32 chunks of 64; wave handles the
// 32-kv half of each chunk for its q-tile: s/w/exp/kc/va all HALVED per wave vs r10
// (unified-reg diet: r7-r10 showed occupancy capped at 2 blocks/CU by VGPR+AGPR).
// Partner waves (same wq, wk 0/1) merge (m,l,acc) through comb LDS overlaid on the
// dead K/V buffers after the sweep; wk=0 stores attnb directly. No z-split/merge kernel.
__global__ __launch_bounds__(256, 2) void attn_kernel(const u16* __restrict__ Qb,
                                                      const u16* __restrict__ Kb,
                                                      const u16* __restrict__ Vt,
                                                      const u64* __restrict__ Mb,
                                                      u16* __restrict__ attnb) {
  // 32KB: [0,8K) Kbuf0, [8K,16K) Kbuf1, [16K,24K) Vbuf0, [24K,32K) Vbuf1.
  // comb (f32 [2][34][64] = 17.4KB) overlays [0,17.4K) after the kv sweep.
  __shared__ u32 smem[8192];
  const int tid = threadIdx.x, lane = tid & 63, w = tid >> 6;
  const int l31 = lane & 31, hi = lane >> 5;
  const int wq = w & 1, wk = w >> 1;
  const int qt = blockIdx.x, bh = blockIdx.y;
  const int h = bh & 15, b = bh >> 4;
  const int q = qt * 64 + wq * 32 + l31;
  const u16* Qp = Qb + (size_t)bh * 2048 * 64;
  const u16* Kp = Kb + (size_t)bh * 2048 * 64;
  const u16* Vp = Vt + (size_t)bh * 64 * 2048;
  const u64* Mrow = Mb + (size_t)q * 32;

  // staging: wave w covers rows [16w,16w+16) of both K and V^T tiles (4 instrs),
  // role-independent (same as r7-r10, validated). XOR-swizzle via pre-swizzled source.
  const int rsub = lane >> 3;                       // 0..7
  const int usrc = ((lane & 7) ^ rsub) * 8;         // pre-swizzled source 16B unit
  auto stage = [&](int bi, int j0) {
#pragma unroll
    for (int j = 0; j < 2; j++) {
      const int i = w * 2 + j;                      // instr index 0..7
      const int row = 8 * i + rsub;
      gload_lds16(Kp + (size_t)(j0 + row) * 64 + usrc, (char*)smem + bi * 8192 + i * 1024);
      gload_lds16(Vp + (size_t)row * 2048 + j0 + usrc, (char*)smem + 16384 + bi * 8192 + i * 1024);
    }
  };

  // Q B-frags: col=q=lane&31, k-half by hi; resident whole kernel
  bf16x8 qf[4];
#pragma unroll
  for (int t = 0; t < 4; t++)
    qf[t] = *(const bf16x8*)&Qp[(size_t)q * 64 + t * 16 + hi * 8];

  f32x16 acc0 = {}, acc1 = {};  // O^T partial (this wave's kv-half): d [0,32)/[32,64), col=q
  float m_run = -3.0e38f, lsum = 0.f;

  stage(0, 0);
  u64 mw = Mrow[0];
  int cur = 0;

  for (int c = 0; c < 32; c++) {
    __syncthreads();  // drains vmcnt: buf[cur] staged; prior reads of buf[cur^1] done
    if (c + 1 < 32) stage(cur ^ 1, (c + 1) * 64);
    u64 mw_n = (c + 1 < 32) ? Mrow[c + 1] : 0;

    const char* Kbase = (const char*)smem + cur * 8192;
    const char* Vbase = (const char*)smem + 16384 + cur * 8192;

    // K frags for this wave's kv-half (swizzled read)
    bf16x8 kc[4];
#pragma unroll
    for (int t = 0; t < 4; t++) {
      const int row = wk * 32 + l31;
      const int u = (t * 2 + hi) ^ (l31 & 7);
      kc[t] = *(const bf16x8*)(Kbase + row * 128 + u * 16);
    }

    // S^T (one 32x32 tile) = K_half · Q^T over d=64 (log2-scaled already)
    f32x16 s = {};
    __builtin_amdgcn_s_setprio(1);
#pragma unroll
    for (int t = 0; t < 4; t++)
      s = __builtin_amdgcn_mfma_f32_32x32x16_bf16(kc[t], qf[t], s, 0, 0, 0);
    __builtin_amdgcn_s_setprio(0);

    // raw row-max over the half (mask applied later by zeroing p), tree + partner
    float mx[8];
#pragma unroll
    for (int i = 0; i < 8; i++) mx[i] = fmaxf(s[i], s[i + 8]);
    float m01 = fmaxf(mx[0], mx[1]), m23 = fmaxf(mx[2], mx[3]);
    float m45 = fmaxf(mx[4], mx[5]), m67 = fmaxf(mx[6], mx[7]);
    float pm = fmaxf(fmaxf(m01, m23), fmaxf(m45, m67));
    pm = fmaxf(pm, __shfl_xor(pm, 32, 64));

    // deferred rescale (THR=8 in log2 domain -> p bounded by 256)
    if (__any(pm > m_run + 8.f)) {
      float mn = fmaxf(m_run, pm);
      float fs = exp2_fast(m_run - mn);
      m_run = mn;
      lsum *= fs;
      acc0 *= fs;
      acc1 *= fs;
    }

    // p = exp2(s - m), mask-zero (this wave's 32-bit mask half), pack kv-pairs
    u32 msel = wk ? (u32)(mw >> 32) : (u32)mw;
    u32 wsh = msel >> (4 * hi);
    u32 wwd[8];
#pragma unroll
    for (int p = 0; p < 8; p++) {
      const int r0 = 2 * p;
      const int sh = (r0 & 3) + 8 * (p >> 1);  // kv_local - 4*hi for reg r0
      float a0 = exp2_fast(s[r0] - m_run);
      float a1 = exp2_fast(s[r0 + 1] - m_run);
      a0 = ((wsh >> sh) & 1u) ? a0 : 0.f;
      a1 = ((wsh >> (sh + 1)) & 1u) ? a1 : 0.f;
      lsum += a0 + a1;
      wwd[p] = (u32)f2b(a0) | ((u32)f2b(a1) << 16);
    }

    // V frags for this wave's kv-half (on-demand: short live range)
    bf16x8 va[2][2];
#pragma unroll
    for (int dt = 0; dt < 2; dt++)
#pragma unroll
      for (int kk = 0; kk < 2; kk++) {
        const int row = dt * 32 + l31;
        const int u = (wk * 4 + kk * 2 + hi) ^ (l31 & 7);
        va[dt][kk] = *(const bf16x8*)(Vbase + row * 128 + u * 16);
      }

    // PV: B-frags via in-register half-exchange (validated r9/r10), kk over 2 k-slices
    __builtin_amdgcn_s_setprio(1);
#pragma unroll
    for (int kk = 0; kk < 2; kk++) {
      const int b4 = kk * 4;
      u32 a0w = wwd[b4 + 0], a1w = wwd[b4 + 1], a2w = wwd[b4 + 2], a3w = wwd[b4 + 3];
      u32 e0 = __shfl_xor(hi ? a0w : a2w, 32, 64);
      u32 e1 = __shfl_xor(hi ? a1w : a3w, 32, 64);
      u32 f0 = hi ? e0 : a0w;
      u32 f1 = hi ? e1 : a1w;
      u32 f2c = hi ? a2w : e0;
      u32 f3 = hi ? a3w : e1;
      u32x4v pv4 = {f0, f1, f2c, f3};
      bf16x8 pbf = __builtin_bit_cast(bf16x8, pv4);
      acc0 = __builtin_amdgcn_mfma_f32_32x32x16_bf16(va[0][kk], pbf, acc0, 0, 0, 0);
      acc1 = __builtin_amdgcn_mfma_f32_32x32x16_bf16(va[1][kk], pbf, acc1, 0, 0, 0);
    }
    __builtin_amdgcn_s_setprio(0);

    mw = mw_n;
    cur ^= 1;
  }

  // ---- in-block merge of kv-half partials (comb overlays dead K/V LDS) ----
  lsum += __shfl_xor(lsum, 32, 64);  // combine hi halves: lsum now per-q total for this half
  __syncthreads();                   // all K/V reads done before comb overwrites
  float* comb = (float*)smem;        // [2][34][64] f32 = 17.4KB
  float* cb = comb + wq * 34 * 64;
  if (wk == 1) {
    cb[0 * 64 + lane] = m_run;
    cb[1 * 64 + lane] = lsum;
#pragma unroll
    for (int r = 0; r < 16; r++) {
      cb[(2 + r) * 64 + lane]  = acc0[r];
      cb[(18 + r) * 64 + lane] = acc1[r];
    }
  }
  __syncthreads();
  if (wk == 0) {
    float mB = cb[0 * 64 + lane];
    float lB_ = cb[1 * 64 + lane];
    float mT = fmaxf(m_run, mB);
    float fA = exp2_fast(m_run - mT);
    float fB = exp2_fast(mB - mT);
    float lt = lsum * fA + lB_ * fB;
    float ia = fA / lt, ib = fB / lt;
#pragma unroll
    for (int r = 0; r < 16; r++) {
      acc0[r] = acc0[r] * ia + cb[(2 + r) * 64 + lane] * ib;
      acc1[r] = acc1[r] * ia + cb[(18 + r) * 64 + lane] * ib;
    }
    u16* orow = attnb + ((size_t)b * 2048 + q) * 1024 + h * 64;
#pragma unroll
    for (int rq = 0; rq < 4; rq++) {
      const int rb = rq * 4;
      {
        u32 lo = (u32)f2b(acc0[rb]) | ((u32)f2b(acc0[rb + 1]) << 16);
        u32 hi2 = (u32)f2b(acc0[rb + 2]) | ((u32)f2b(acc0[rb + 3]) << 16);
        uint2 st; st.x = lo; st.y = hi2;
        *(uint2*)(orow + 8 * rq + 4 * hi) = st;
      }
      {
        u32 lo = (u32)f2b(acc1[rb]) | ((u32)f2b(acc1[rb + 1]) << 16);
        u32 hi2 = (u32)f2b(acc1[rb + 2]) | ((u32)f2b(acc1[rb + 3]) << 16);
        uint2 st; st.x = lo; st.y = hi2;
        *(uint2*)(orow + 32 + 8 * rq + 4 * hi) = st;
      }
    }
  }
}

extern "C" void kernel_launch(void* const* d_in, const int* in_sizes, int n_in,
                              void* d_out, int out_size, void* d_ws, size_t ws_size,
                              hipStream_t stream) {
  const float* x    = (const float*)d_in[0];
  const int*   mask = (const int*)d_in[1];
  const float* Wqkv = (const float*)d_in[2];
  const float* Wout = (const float*)d_in[3];
  const float* bout = (const float*)d_in[4];
  float* out = (float*)d_out;

  char* ws = (char*)d_ws;
  // layout (bytes): [0,8M) xb / attnb; [8,14M) Wqkv_t -> [8,10M) Wout_t + [10,10.5M) mbits;
  // [14,22M) Qb; [22,30M) Kb; [30,38M) Vt
  u16* xb     = (u16*)(ws);
  u16* attnb  = xb;
  u16* Wqkv_t = (u16*)(ws + (size_t)(8u << 20));
  u16* Wout_t = Wqkv_t;
  u64* mbits  = (u64*)(ws + (size_t)(10u << 20));
  u16* Qb     = (u16*)(ws + (size_t)(14u << 20));
  u16* Kb     = (u16*)(ws + (size_t)(22u << 20));
  u16* Vt     = (u16*)(ws + (size_t)(30u << 20));

  cast_bf16_kernel<<<4096, 256, 0, stream>>>(x, xb, 4096 * 1024 / 4);
  transpose_cast_kernel<<<dim3(96, 32), dim3(32, 8), 0, stream>>>(Wqkv, Wqkv_t, 1024, 3072);
  gemm_qkv_kernel<<<dim3(24, 32), 256, 0, stream>>>(xb, Wqkv_t, Qb, Kb, Vt);
  transpose_cast_kernel<<<dim3(32, 32), dim3(32, 8), 0, stream>>>(Wout, Wout_t, 1024, 1024);
  maskbits_kernel<<<16384, 256, 0, stream>>>(mask, mbits);
  attn_kernel<<<dim3(32, 32), 256, 0, stream>>>(Qb, Kb, Vt, mbits, attnb);
  gemm_out_kernel<<<dim3(8, 32), 256, 0, stream>>>(attnb, Wout_t, bout, out);
}

// Round 12
// 154.744 us; speedup vs baseline: 1.2527x; 1.0301x over previous
//
#include <hip/hip_runtime.h>
#include <hip/hip_bf16.h>

typedef __bf16 bf16x8 __attribute__((ext_vector_type(8)));
typedef float f32x4 __attribute__((ext_vector_type(4)));
typedef float f32x16 __attribute__((ext_vector_type(16)));
typedef unsigned short u16;
typedef unsigned int u32;
typedef unsigned long long u64;
typedef u32 u32x4v __attribute__((ext_vector_type(4)));

#define QSCALE 0.18033688011112042f  /* log2(e)/8 : folds SCALE and exp->exp2 into Q */

__device__ __forceinline__ u16 f2b(float x) {
  __hip_bfloat16 h = __float2bfloat16(x);
  return __builtin_bit_cast(u16, h);
}

__device__ __forceinline__ float exp2_fast(float x) {
#if __has_builtin(__builtin_amdgcn_exp2f)
  return __builtin_amdgcn_exp2f(x);
#else
  float r; asm("v_exp_f32 %0, %1" : "=v"(r) : "v"(x)); return r;
#endif
}

// async global->LDS, 16B per lane; LDS dest = wave-uniform base + lane*16
__device__ __forceinline__ void gload_lds16(const void* g, void* l) {
  __builtin_amdgcn_global_load_lds((const __attribute__((address_space(1))) u32*)g,
                                   (__attribute__((address_space(3))) u32*)l, 16, 0, 0);
}

// ---------------- cast f32 -> bf16 (4 elems/thread) ----------------
__global__ __launch_bounds__(256) void cast_bf16_kernel(const float* __restrict__ src,
                                                        u16* __restrict__ dst, int n4) {
  int i = blockIdx.x * 256 + threadIdx.x;
  if (i >= n4) return;
  float4 v = ((const float4*)src)[i];
  ushort4 o;
  o.x = f2b(v.x); o.y = f2b(v.y); o.z = f2b(v.z); o.w = f2b(v.w);
  ((ushort4*)dst)[i] = o;
}

// ---------------- transpose+cast: src [R][C] f32 -> dst [C][R] bf16 ----------------
__global__ __launch_bounds__(256) void transpose_cast_kernel(const float* __restrict__ src,
                                                             u16* __restrict__ dst,
                                                             int R, int C) {
  __shared__ float t[32][33];
  int c0 = blockIdx.x * 32, r0 = blockIdx.y * 32;
  int tx = threadIdx.x, ty = threadIdx.y;
  for (int k = 0; k < 32; k += 8)
    t[ty + k][tx] = src[(size_t)(r0 + ty + k) * C + c0 + tx];
  __syncthreads();
  for (int k = 0; k < 32; k += 8)
    dst[(size_t)(c0 + ty + k) * R + r0 + tx] = f2b(t[tx][ty + k]);
}

// ---------------- mask [2048][2048] int32 -> bit-packed u64 words ----------------
__global__ __launch_bounds__(256) void maskbits_kernel(const int* __restrict__ mask,
                                                       u64* __restrict__ bits) {
  int gtid = blockIdx.x * 256 + threadIdx.x;
  int wid = gtid >> 6, lane = gtid & 63;
  int v = mask[(size_t)wid * 64 + lane];
  u64 b = __ballot(v != 0);
  if (lane == 0) bits[wid] = b;
}

// ---------------- QKV GEMM: xb[4096][1024] @ Wqkv_t[3072][1024]^T ----------------
// m97 structure: global_load_lds(16B) staging, 2 barriers per K-step.
// Epilogue scatters into Qb (pre-scaled by QSCALE) / Kb [B][H][N][64], Vt [B][H][64][N].
__global__ __launch_bounds__(256) void gemm_qkv_kernel(const u16* __restrict__ A,
                                                       const u16* __restrict__ Bt,
                                                       u16* __restrict__ Qb,
                                                       u16* __restrict__ Kb,
                                                       u16* __restrict__ Vt) {
  __shared__ u16 lA[128 * 32], lB[128 * 32];
  const int tid = threadIdx.x, lane = tid & 63, w = tid >> 6;
  const int wr = w >> 1, wc = w & 1, lrow = lane & 15, lk = lane >> 4;
  const int bm = blockIdx.y, bn = blockIdx.x;
  const int srow = tid >> 2, scol = (tid & 3) * 8;
  const u16* Arow = A + (size_t)(bm * 128 + srow) * 1024 + scol;
  const u16* Brow = Bt + (size_t)(bn * 128 + srow) * 1024 + scol;
  f32x4 acc[4][4] = {};
  for (int k0 = 0; k0 < 1024; k0 += 32) {
    __syncthreads();  // prior iteration's ds_reads done before overwrite
    gload_lds16(Arow + k0,             (char*)lA + w * 1024);
    gload_lds16(Arow + 64 * 1024 + k0, (char*)lA + 4096 + w * 1024);
    gload_lds16(Brow + k0,             (char*)lB + w * 1024);
    gload_lds16(Brow + 64 * 1024 + k0, (char*)lB + 4096 + w * 1024);
    __syncthreads();  // drains vmcnt: staged data visible
    bf16x8 af[4], bfr[4];
    for (int mi = 0; mi < 4; mi++)
      af[mi] = *(const bf16x8*)&lA[(wr * 64 + mi * 16 + lrow) * 32 + lk * 8];
    for (int ni = 0; ni < 4; ni++)
      bfr[ni] = *(const bf16x8*)&lB[(wc * 64 + ni * 16 + lrow) * 32 + lk * 8];
    for (int mi = 0; mi < 4; mi++)
      for (int ni = 0; ni < 4; ni++)
        acc[mi][ni] = __builtin_amdgcn_mfma_f32_16x16x32_bf16(af[mi], bfr[ni], acc[mi][ni], 0, 0, 0);
  }
  const int rowbase = bm * 128 + wr * 64;
  const int colbase = bn * 128 + wc * 64;
  for (int mi = 0; mi < 4; mi++)
    for (int ni = 0; ni < 4; ni++)
      for (int r = 0; r < 4; r++) {
        int row = rowbase + mi * 16 + lk * 4 + r;
        int col = colbase + ni * 16 + lrow;
        int b = row >> 11, n = row & 2047;
        int which = col >> 10, within = col & 1023;
        int h = within >> 6, d = within & 63;
        float av = acc[mi][ni][r];
        size_t bh = (size_t)(b * 16 + h);
        if (which == 0)      Qb[(bh * 2048 + n) * 64 + d] = f2b(av * QSCALE);
        else if (which == 1) Kb[(bh * 2048 + n) * 64 + d] = f2b(av);
        else                 Vt[(bh * 64 + d) * 2048 + n] = f2b(av);
      }
}

// ---------------- out-proj GEMM: attnb[4096][1024] @ Wout_t[1024][1024]^T + bias ----
// Retiled 64(M)x128(N), grid (8, 64) = 512 blocks (2/CU; was 256 = 1/CU and
// fully latency-exposed). Staging: A = 1 gload_lds16/wave, B = 2.
__global__ __launch_bounds__(256) void gemm_out_kernel(const u16* __restrict__ A,
                                                       const u16* __restrict__ Bt,
                                                       const float* __restrict__ bias,
                                                       float* __restrict__ out) {
  __shared__ u16 lA[64 * 32], lB[128 * 32];
  const int tid = threadIdx.x, lane = tid & 63, w = tid >> 6;
  const int wr = w >> 1, wc = w & 1, lrow = lane & 15, lk = lane >> 4;
  const int bn = blockIdx.x, bm = blockIdx.y;
  const u16* Arow  = A  + (size_t)(bm * 64 + w * 16 + (lane >> 2)) * 1024 + (lane & 3) * 8;
  const u16* Brow0 = Bt + (size_t)(bn * 128 + (w * 2) * 16 + (lane >> 2)) * 1024 + (lane & 3) * 8;
  const u16* Brow1 = Brow0 + 16 * 1024;
  f32x4 acc[2][4] = {};
  for (int k0 = 0; k0 < 1024; k0 += 32) {
    __syncthreads();
    gload_lds16(Arow + k0,  (char*)lA + w * 1024);
    gload_lds16(Brow0 + k0, (char*)lB + (w * 2) * 1024);
    gload_lds16(Brow1 + k0, (char*)lB + (w * 2 + 1) * 1024);
    __syncthreads();
    bf16x8 af[2], bfr[4];
    for (int mi = 0; mi < 2; mi++)
      af[mi] = *(const bf16x8*)&lA[(wr * 32 + mi * 16 + lrow) * 32 + lk * 8];
    for (int ni = 0; ni < 4; ni++)
      bfr[ni] = *(const bf16x8*)&lB[(wc * 64 + ni * 16 + lrow) * 32 + lk * 8];
    for (int mi = 0; mi < 2; mi++)
      for (int ni = 0; ni < 4; ni++)
        acc[mi][ni] = __builtin_amdgcn_mfma_f32_16x16x32_bf16(af[mi], bfr[ni], acc[mi][ni], 0, 0, 0);
  }
  const int rowbase = bm * 64 + wr * 32;
  const int colbase = bn * 128 + wc * 64;
  for (int mi = 0; mi < 2; mi++)
    for (int ni = 0; ni < 4; ni++)
      for (int r = 0; r < 4; r++) {
        int row = rowbase + mi * 16 + lk * 4 + r;
        int col = colbase + ni * 16 + lrow;
        out[(size_t)row * 1024 + col] = acc[mi][ni][r] + bias[col];
      }
}

// ---------------- flash attention: swapped QK^T (32x32), kv-half wave split ----
// grid (32, 32), block 256 = 4 waves: wave = (wq = w&1 q-tile, wk = w>>1 kv-half).
// Block covers 64 q-rows, sweeps all 2048 kv in 32 chunks of 64; wave handles the
// 32-kv half of each chunk for its q-tile. Partner waves merge via comb LDS overlay.
// __launch_bounds__(256,3): cap unified regs at the 3-blocks/CU budget (r11's (256,2)
// let the allocator spend up to 2-waves/SIMD budget -> occupancy stuck at ~2 blocks/CU).
__global__ __launch_bounds__(256, 3) void attn_kernel(const u16* __restrict__ Qb,
                                                      const u16* __restrict__ Kb,
                                                      const u16* __restrict__ Vt,
                                                      const u64* __restrict__ Mb,
                                                      u16* __restrict__ attnb) {
  // 32KB: [0,8K) Kbuf0, [8K,16K) Kbuf1, [16K,24K) Vbuf0, [24K,32K) Vbuf1.
  // comb (f32 [2][34][64] = 17.4KB) overlays [0,17.4K) after the kv sweep.
  __shared__ u32 smem[8192];
  const int tid = threadIdx.x, lane = tid & 63, w = tid >> 6;
  const int l31 = lane & 31, hi = lane >> 5;
  const int wq = w & 1, wk = w >> 1;
  const int qt = blockIdx.x, bh = blockIdx.y;
  const int h = bh & 15, b = bh >> 4;
  const int q = qt * 64 + wq * 32 + l31;
  const u16* Qp = Qb + (size_t)bh * 2048 * 64;
  const u16* Kp = Kb + (size_t)bh * 2048 * 64;
  const u16* Vp = Vt + (size_t)bh * 64 * 2048;
  const u64* Mrow = Mb + (size_t)q * 32;

  // staging: wave w covers rows [16w,16w+16) of both K and V^T tiles (4 instrs),
  // role-independent. XOR-swizzle via pre-swizzled source (rule #21 both-sides).
  const int rsub = lane >> 3;                       // 0..7
  const int usrc = ((lane & 7) ^ rsub) * 8;         // pre-swizzled source 16B unit
  auto stage = [&](int bi, int j0) {
#pragma unroll
    for (int j = 0; j < 2; j++) {
      const int i = w * 2 + j;                      // instr index 0..7
      const int row = 8 * i + rsub;
      gload_lds16(Kp + (size_t)(j0 + row) * 64 + usrc, (char*)smem + bi * 8192 + i * 1024);
      gload_lds16(Vp + (size_t)row * 2048 + j0 + usrc, (char*)smem + 16384 + bi * 8192 + i * 1024);
    }
  };

  // Q B-frags: col=q=lane&31, k-half by hi; resident whole kernel
  bf16x8 qf[4];
#pragma unroll
  for (int t = 0; t < 4; t++)
    qf[t] = *(const bf16x8*)&Qp[(size_t)q * 64 + t * 16 + hi * 8];

  f32x16 acc0 = {}, acc1 = {};  // O^T partial (this wave's kv-half): d [0,32)/[32,64), col=q
  float m_run = -3.0e38f, lsum = 0.f;

  stage(0, 0);
  u64 mw = Mrow[0];
  int cur = 0;

  for (int c = 0; c < 32; c++) {
    __syncthreads();  // drains vmcnt: buf[cur] staged; prior reads of buf[cur^1] done
    if (c + 1 < 32) stage(cur ^ 1, (c + 1) * 64);
    u64 mw_n = (c + 1 < 32) ? Mrow[c + 1] : 0;

    const char* Kbase = (const char*)smem + cur * 8192;
    const char* Vbase = (const char*)smem + 16384 + cur * 8192;

    // K frags for this wave's kv-half (swizzled read)
    bf16x8 kc[4];
#pragma unroll
    for (int t = 0; t < 4; t++) {
      const int row = wk * 32 + l31;
      const int u = (t * 2 + hi) ^ (l31 & 7);
      kc[t] = *(const bf16x8*)(Kbase + row * 128 + u * 16);
    }

    // S^T (one 32x32 tile) = K_half · Q^T over d=64 (log2-scaled already)
    f32x16 s = {};
    __builtin_amdgcn_s_setprio(1);
#pragma unroll
    for (int t = 0; t < 4; t++)
      s = __builtin_amdgcn_mfma_f32_32x32x16_bf16(kc[t], qf[t], s, 0, 0, 0);
    __builtin_amdgcn_s_setprio(0);

    // raw row-max over the half (mask applied later by zeroing p), tree + partner
    float mx[8];
#pragma unroll
    for (int i = 0; i < 8; i++) mx[i] = fmaxf(s[i], s[i + 8]);
    float m01 = fmaxf(mx[0], mx[1]), m23 = fmaxf(mx[2], mx[3]);
    float m45 = fmaxf(mx[4], mx[5]), m67 = fmaxf(mx[6], mx[7]);
    float pm = fmaxf(fmaxf(m01, m23), fmaxf(m45, m67));
    pm = fmaxf(pm, __shfl_xor(pm, 32, 64));

    // deferred rescale (THR=8 in log2 domain -> p bounded by 256)
    if (__any(pm > m_run + 8.f)) {
      float mn = fmaxf(m_run, pm);
      float fs = exp2_fast(m_run - mn);
      m_run = mn;
      lsum *= fs;
      acc0 *= fs;
      acc1 *= fs;
    }

    // p = exp2(s - m), mask-zero (this wave's 32-bit mask half), pack kv-pairs
    u32 msel = wk ? (u32)(mw >> 32) : (u32)mw;
    u32 wsh = msel >> (4 * hi);
    u32 wwd[8];
#pragma unroll
    for (int p = 0; p < 8; p++) {
      const int r0 = 2 * p;
      const int sh = (r0 & 3) + 8 * (p >> 1);  // kv_local - 4*hi for reg r0
      float a0 = exp2_fast(s[r0] - m_run);
      float a1 = exp2_fast(s[r0 + 1] - m_run);
      a0 = ((wsh >> sh) & 1u) ? a0 : 0.f;
      a1 = ((wsh >> (sh + 1)) & 1u) ? a1 : 0.f;
      lsum += a0 + a1;
      wwd[p] = (u32)f2b(a0) | ((u32)f2b(a1) << 16);
    }

    // V frags for this wave's kv-half (on-demand: short live range)
    bf16x8 va[2][2];
#pragma unroll
    for (int dt = 0; dt < 2; dt++)
#pragma unroll
      for (int kk = 0; kk < 2; kk++) {
        const int row = dt * 32 + l31;
        const int u = (wk * 4 + kk * 2 + hi) ^ (l31 & 7);
        va[dt][kk] = *(const bf16x8*)(Vbase + row * 128 + u * 16);
      }

    // PV: B-frags via in-register half-exchange (validated r9/r10), kk over 2 k-slices
    __builtin_amdgcn_s_setprio(1);
#pragma unroll
    for (int kk = 0; kk < 2; kk++) {
      const int b4 = kk * 4;
      u32 a0w = wwd[b4 + 0], a1w = wwd[b4 + 1], a2w = wwd[b4 + 2], a3w = wwd[b4 + 3];
      u32 e0 = __shfl_xor(hi ? a0w : a2w, 32, 64);
      u32 e1 = __shfl_xor(hi ? a1w : a3w, 32, 64);
      u32 f0 = hi ? e0 : a0w;
      u32 f1 = hi ? e1 : a1w;
      u32 f2c = hi ? a2w : e0;
      u32 f3 = hi ? a3w : e1;
      u32x4v pv4 = {f0, f1, f2c, f3};
      bf16x8 pbf = __builtin_bit_cast(bf16x8, pv4);
      acc0 = __builtin_amdgcn_mfma_f32_32x32x16_bf16(va[0][kk], pbf, acc0, 0, 0, 0);
      acc1 = __builtin_amdgcn_mfma_f32_32x32x16_bf16(va[1][kk], pbf, acc1, 0, 0, 0);
    }
    __builtin_amdgcn_s_setprio(0);

    mw = mw_n;
    cur ^= 1;
  }

  // ---- in-block merge of kv-half partials (comb overlays dead K/V LDS) ----
  lsum += __shfl_xor(lsum, 32, 64);  // combine hi halves: lsum now per-q total for this half
  __syncthreads();                   // all K/V reads done before comb overwrites
  float* comb = (float*)smem;        // [2][34][64] f32 = 17.4KB
  float* cb = comb + wq * 34 * 64;
  if (wk == 1) {
    cb[0 * 64 + lane] = m_run;
    cb[1 * 64 + lane] = lsum;
#pragma unroll
    for (int r = 0; r < 16; r++) {
      cb[(2 + r) * 64 + lane]  = acc0[r];
      cb[(18 + r) * 64 + lane] = acc1[r];
    }
  }
  __syncthreads();
  if (wk == 0) {
    float mB = cb[0 * 64 + lane];
    float lB_ = cb[1 * 64 + lane];
    float mT = fmaxf(m_run, mB);
    float fA = exp2_fast(m_run - mT);
    float fB = exp2_fast(mB - mT);
    float lt = lsum * fA + lB_ * fB;
    float ia = fA / lt, ib = fB / lt;
#pragma unroll
    for (int r = 0; r < 16; r++) {
      acc0[r] = acc0[r] * ia + cb[(2 + r) * 64 + lane] * ib;
      acc1[r] = acc1[r] * ia + cb[(18 + r) * 64 + lane] * ib;
    }
    u16* orow = attnb + ((size_t)b * 2048 + q) * 1024 + h * 64;
#pragma unroll
    for (int rq = 0; rq < 4; rq++) {
      const int rb = rq * 4;
      {
        u32 lo = (u32)f2b(acc0[rb]) | ((u32)f2b(acc0[rb + 1]) << 16);
        u32 hi2 = (u32)f2b(acc0[rb + 2]) | ((u32)f2b(acc0[rb + 3]) << 16);
        uint2 st; st.x = lo; st.y = hi2;
        *(uint2*)(orow + 8 * rq + 4 * hi) = st;
      }
      {
        u32 lo = (u32)f2b(acc1[rb]) | ((u32)f2b(acc1[rb + 1]) << 16);
        u32 hi2 = (u32)f2b(acc1[rb + 2]) | ((u32)f2b(acc1[rb + 3]) << 16);
        uint2 st; st.x = lo; st.y = hi2;
        *(uint2*)(orow + 32 + 8 * rq + 4 * hi) = st;
      }
    }
  }
}

extern "C" void kernel_launch(void* const* d_in, const int* in_sizes, int n_in,
                              void* d_out, int out_size, void* d_ws, size_t ws_size,
                              hipStream_t stream) {
  const float* x    = (const float*)d_in[0];
  const int*   mask = (const int*)d_in[1];
  const float* Wqkv = (const float*)d_in[2];
  const float* Wout = (const float*)d_in[3];
  const float* bout = (const float*)d_in[4];
  float* out = (float*)d_out;

  char* ws = (char*)d_ws;
  // layout (bytes): [0,8M) xb / attnb; [8,14M) Wqkv_t -> [8,10M) Wout_t + [10,10.5M) mbits;
  // [14,22M) Qb; [22,30M) Kb; [30,38M) Vt
  u16* xb     = (u16*)(ws);
  u16* attnb  = xb;
  u16* Wqkv_t = (u16*)(ws + (size_t)(8u << 20));
  u16* Wout_t = Wqkv_t;
  u64* mbits  = (u64*)(ws + (size_t)(10u << 20));
  u16* Qb     = (u16*)(ws + (size_t)(14u << 20));
  u16* Kb     = (u16*)(ws + (size_t)(22u << 20));
  u16* Vt     = (u16*)(ws + (size_t)(30u << 20));

  cast_bf16_kernel<<<4096, 256, 0, stream>>>(x, xb, 4096 * 1024 / 4);
  transpose_cast_kernel<<<dim3(96, 32), dim3(32, 8), 0, stream>>>(Wqkv, Wqkv_t, 1024, 3072);
  gemm_qkv_kernel<<<dim3(24, 32), 256, 0, stream>>>(xb, Wqkv_t, Qb, Kb, Vt);
  transpose_cast_kernel<<<dim3(32, 32), dim3(32, 8), 0, stream>>>(Wout, Wout_t, 1024, 1024);
  maskbits_kernel<<<16384, 256, 0, stream>>>(mask, mbits);
  attn_kernel<<<dim3(32, 32), 256, 0, stream>>>(Qb, Kb, Vt, mbits, attnb);
  gemm_out_kernel<<<dim3(8, 64), 256, 0, stream>>>(attnb, Wout_t, bout, out);
}

// Round 13
// 147.958 us; speedup vs baseline: 1.3101x; 1.0459x over previous
//
#include <hip/hip_runtime.h>
#include <hip/hip_bf16.h>

typedef __bf16 bf16x8 __attribute__((ext_vector_type(8)));
typedef float f32x4 __attribute__((ext_vector_type(4)));
typedef float f32x16 __attribute__((ext_vector_type(16)));
typedef unsigned short u16;
typedef unsigned int u32;
typedef unsigned long long u64;
typedef u32 u32x4v __attribute__((ext_vector_type(4)));

#define QSCALE 0.18033688011112042f  /* log2(e)/8 : folds SCALE and exp->exp2 into Q */

__device__ __forceinline__ u16 f2b(float x) {
  __hip_bfloat16 h = __float2bfloat16(x);
  return __builtin_bit_cast(u16, h);
}

__device__ __forceinline__ float exp2_fast(float x) {
#if __has_builtin(__builtin_amdgcn_exp2f)
  return __builtin_amdgcn_exp2f(x);
#else
  float r; asm("v_exp_f32 %0, %1" : "=v"(r) : "v"(x)); return r;
#endif
}

// async global->LDS, 16B per lane; LDS dest = wave-uniform base + lane*16
__device__ __forceinline__ void gload_lds16(const void* g, void* l) {
  __builtin_amdgcn_global_load_lds((const __attribute__((address_space(1))) u32*)g,
                                   (__attribute__((address_space(3))) u32*)l, 16, 0, 0);
}

// ---------------- fused preprocessing: maskbits | cast | transpose Wqkv | transpose Wout ----
// One launch replaces 4 (saves ~3 graph-replay gaps). Branch is block-uniform.
// [0,16384): mask [2048][2048] i32 -> bit-packed u64
// [16384,20480): x f32 -> bf16 (4 elems/thread)
// [20480,23552): Wqkv [1024][3072] -> [3072][1024] bf16
// [23552,24576): Wout [1024][1024] -> [1024][1024]^T bf16
__global__ __launch_bounds__(256) void prep_kernel(const float* __restrict__ x,
                                                   const int* __restrict__ mask,
                                                   const float* __restrict__ Wqkv,
                                                   const float* __restrict__ Wout,
                                                   u16* __restrict__ xb,
                                                   u64* __restrict__ mbits,
                                                   u16* __restrict__ Wqkv_t,
                                                   u16* __restrict__ Wout_t) {
  const int bid = blockIdx.x, tid = threadIdx.x;
  if (bid < 16384) {
    // maskbits
    int gtid = bid * 256 + tid;
    int wid = gtid >> 6, lane = gtid & 63;
    int v = mask[(size_t)wid * 64 + lane];
    u64 b = __ballot(v != 0);
    if (lane == 0) mbits[wid] = b;
    return;
  }
  if (bid < 20480) {
    // cast x -> bf16
    int i = (bid - 16384) * 256 + tid;
    float4 v = ((const float4*)x)[i];
    ushort4 o;
    o.x = f2b(v.x); o.y = f2b(v.y); o.z = f2b(v.z); o.w = f2b(v.w);
    ((ushort4*)xb)[i] = o;
    return;
  }
  // transpose+cast branch (block-uniform; __syncthreads safe)
  __shared__ float t[32][33];
  const float* src; u16* dst; int R, C, c0, r0;
  if (bid < 23552) {
    int local = bid - 20480;            // 96 x 32 tiles
    src = Wqkv; dst = Wqkv_t; R = 1024; C = 3072;
    c0 = (local % 96) * 32; r0 = (local / 96) * 32;
  } else {
    int local = bid - 23552;            // 32 x 32 tiles
    src = Wout; dst = Wout_t; R = 1024; C = 1024;
    c0 = (local % 32) * 32; r0 = (local / 32) * 32;
  }
  const int tx = tid & 31, ty = tid >> 5;   // (32, 8)
  for (int k = 0; k < 32; k += 8)
    t[ty + k][tx] = src[(size_t)(r0 + ty + k) * C + c0 + tx];
  __syncthreads();
  for (int k = 0; k < 32; k += 8)
    dst[(size_t)(c0 + ty + k) * R + r0 + tx] = f2b(t[tx][ty + k]);
}

// ---------------- QKV GEMM: xb[4096][1024] @ Wqkv_t[3072][1024]^T ----------------
// m97 structure: global_load_lds(16B) staging, 2 barriers per K-step.
// Epilogue scatters into Qb (pre-scaled by QSCALE) / Kb [B][H][N][64], Vt [B][H][64][N].
__global__ __launch_bounds__(256) void gemm_qkv_kernel(const u16* __restrict__ A,
                                                       const u16* __restrict__ Bt,
                                                       u16* __restrict__ Qb,
                                                       u16* __restrict__ Kb,
                                                       u16* __restrict__ Vt) {
  __shared__ u16 lA[128 * 32], lB[128 * 32];
  const int tid = threadIdx.x, lane = tid & 63, w = tid >> 6;
  const int wr = w >> 1, wc = w & 1, lrow = lane & 15, lk = lane >> 4;
  const int bm = blockIdx.y, bn = blockIdx.x;
  const int srow = tid >> 2, scol = (tid & 3) * 8;
  const u16* Arow = A + (size_t)(bm * 128 + srow) * 1024 + scol;
  const u16* Brow = Bt + (size_t)(bn * 128 + srow) * 1024 + scol;
  f32x4 acc[4][4] = {};
  for (int k0 = 0; k0 < 1024; k0 += 32) {
    __syncthreads();  // prior iteration's ds_reads done before overwrite
    gload_lds16(Arow + k0,             (char*)lA + w * 1024);
    gload_lds16(Arow + 64 * 1024 + k0, (char*)lA + 4096 + w * 1024);
    gload_lds16(Brow + k0,             (char*)lB + w * 1024);
    gload_lds16(Brow + 64 * 1024 + k0, (char*)lB + 4096 + w * 1024);
    __syncthreads();  // drains vmcnt: staged data visible
    bf16x8 af[4], bfr[4];
    for (int mi = 0; mi < 4; mi++)
      af[mi] = *(const bf16x8*)&lA[(wr * 64 + mi * 16 + lrow) * 32 + lk * 8];
    for (int ni = 0; ni < 4; ni++)
      bfr[ni] = *(const bf16x8*)&lB[(wc * 64 + ni * 16 + lrow) * 32 + lk * 8];
    for (int mi = 0; mi < 4; mi++)
      for (int ni = 0; ni < 4; ni++)
        acc[mi][ni] = __builtin_amdgcn_mfma_f32_16x16x32_bf16(af[mi], bfr[ni], acc[mi][ni], 0, 0, 0);
  }
  const int rowbase = bm * 128 + wr * 64;
  const int colbase = bn * 128 + wc * 64;
  for (int mi = 0; mi < 4; mi++)
    for (int ni = 0; ni < 4; ni++)
      for (int r = 0; r < 4; r++) {
        int row = rowbase + mi * 16 + lk * 4 + r;
        int col = colbase + ni * 16 + lrow;
        int b = row >> 11, n = row & 2047;
        int which = col >> 10, within = col & 1023;
        int h = within >> 6, d = within & 63;
        float av = acc[mi][ni][r];
        size_t bh = (size_t)(b * 16 + h);
        if (which == 0)      Qb[(bh * 2048 + n) * 64 + d] = f2b(av * QSCALE);
        else if (which == 1) Kb[(bh * 2048 + n) * 64 + d] = f2b(av);
        else                 Vt[(bh * 64 + d) * 2048 + n] = f2b(av);
      }
}

// ---------------- out-proj GEMM: attnb[4096][1024] @ Wout_t[1024][1024]^T + bias ----
// 64(M)x128(N) tile, grid (8, 64) = 512 blocks (2/CU). A = 1 gload/wave, B = 2.
__global__ __launch_bounds__(256) void gemm_out_kernel(const u16* __restrict__ A,
                                                       const u16* __restrict__ Bt,
                                                       const float* __restrict__ bias,
                                                       float* __restrict__ out) {
  __shared__ u16 lA[64 * 32], lB[128 * 32];
  const int tid = threadIdx.x, lane = tid & 63, w = tid >> 6;
  const int wr = w >> 1, wc = w & 1, lrow = lane & 15, lk = lane >> 4;
  const int bn = blockIdx.x, bm = blockIdx.y;
  const u16* Arow  = A  + (size_t)(bm * 64 + w * 16 + (lane >> 2)) * 1024 + (lane & 3) * 8;
  const u16* Brow0 = Bt + (size_t)(bn * 128 + (w * 2) * 16 + (lane >> 2)) * 1024 + (lane & 3) * 8;
  const u16* Brow1 = Brow0 + 16 * 1024;
  f32x4 acc[2][4] = {};
  for (int k0 = 0; k0 < 1024; k0 += 32) {
    __syncthreads();
    gload_lds16(Arow + k0,  (char*)lA + w * 1024);
    gload_lds16(Brow0 + k0, (char*)lB + (w * 2) * 1024);
    gload_lds16(Brow1 + k0, (char*)lB + (w * 2 + 1) * 1024);
    __syncthreads();
    bf16x8 af[2], bfr[4];
    for (int mi = 0; mi < 2; mi++)
      af[mi] = *(const bf16x8*)&lA[(wr * 32 + mi * 16 + lrow) * 32 + lk * 8];
    for (int ni = 0; ni < 4; ni++)
      bfr[ni] = *(const bf16x8*)&lB[(wc * 64 + ni * 16 + lrow) * 32 + lk * 8];
    for (int mi = 0; mi < 2; mi++)
      for (int ni = 0; ni < 4; ni++)
        acc[mi][ni] = __builtin_amdgcn_mfma_f32_16x16x32_bf16(af[mi], bfr[ni], acc[mi][ni], 0, 0, 0);
  }
  const int rowbase = bm * 64 + wr * 32;
  const int colbase = bn * 128 + wc * 64;
  for (int mi = 0; mi < 2; mi++)
    for (int ni = 0; ni < 4; ni++)
      for (int r = 0; r < 4; r++) {
        int row = rowbase + mi * 16 + lk * 4 + r;
        int col = colbase + ni * 16 + lrow;
        out[(size_t)row * 1024 + col] = acc[mi][ni][r] + bias[col];
      }
}

// ---------------- flash attention: swapped QK^T (32x32), kv-half wave split ----
// grid (32, 32), block 256 = 4 waves: wave = (wq = w&1 q-tile, wk = w>>1 kv-half).
// Block covers 64 q-rows, sweeps all 2048 kv in 32 chunks of 64; wave handles the
// 32-kv half of each chunk for its q-tile. Partner waves merge via comb LDS overlay.
__global__ __launch_bounds__(256, 3) void attn_kernel(const u16* __restrict__ Qb,
                                                      const u16* __restrict__ Kb,
                                                      const u16* __restrict__ Vt,
                                                      const u64* __restrict__ Mb,
                                                      u16* __restrict__ attnb) {
  // 32KB: [0,8K) Kbuf0, [8K,16K) Kbuf1, [16K,24K) Vbuf0, [24K,32K) Vbuf1.
  // comb (f32 [2][34][64] = 17.4KB) overlays [0,17.4K) after the kv sweep.
  __shared__ u32 smem[8192];
  const int tid = threadIdx.x, lane = tid & 63, w = tid >> 6;
  const int l31 = lane & 31, hi = lane >> 5;
  const int wq = w & 1, wk = w >> 1;
  const int qt = blockIdx.x, bh = blockIdx.y;
  const int h = bh & 15, b = bh >> 4;
  const int q = qt * 64 + wq * 32 + l31;
  const u16* Qp = Qb + (size_t)bh * 2048 * 64;
  const u16* Kp = Kb + (size_t)bh * 2048 * 64;
  const u16* Vp = Vt + (size_t)bh * 64 * 2048;
  const u64* Mrow = Mb + (size_t)q * 32;

  // staging: wave w covers rows [16w,16w+16) of both K and V^T tiles (4 instrs),
  // role-independent. XOR-swizzle via pre-swizzled source (rule #21 both-sides).
  const int rsub = lane >> 3;                       // 0..7
  const int usrc = ((lane & 7) ^ rsub) * 8;         // pre-swizzled source 16B unit
  auto stage = [&](int bi, int j0) {
#pragma unroll
    for (int j = 0; j < 2; j++) {
      const int i = w * 2 + j;                      // instr index 0..7
      const int row = 8 * i + rsub;
      gload_lds16(Kp + (size_t)(j0 + row) * 64 + usrc, (char*)smem + bi * 8192 + i * 1024);
      gload_lds16(Vp + (size_t)row * 2048 + j0 + usrc, (char*)smem + 16384 + bi * 8192 + i * 1024);
    }
  };

  // Q B-frags: col=q=lane&31, k-half by hi; resident whole kernel
  bf16x8 qf[4];
#pragma unroll
  for (int t = 0; t < 4; t++)
    qf[t] = *(const bf16x8*)&Qp[(size_t)q * 64 + t * 16 + hi * 8];

  f32x16 acc0 = {}, acc1 = {};  // O^T partial (this wave's kv-half): d [0,32)/[32,64), col=q
  float m_run = -3.0e38f, lsum = 0.f;

  stage(0, 0);
  u64 mw = Mrow[0];
  int cur = 0;

  for (int c = 0; c < 32; c++) {
    __syncthreads();  // drains vmcnt: buf[cur] staged; prior reads of buf[cur^1] done
    if (c + 1 < 32) stage(cur ^ 1, (c + 1) * 64);
    u64 mw_n = (c + 1 < 32) ? Mrow[c + 1] : 0;

    const char* Kbase = (const char*)smem + cur * 8192;
    const char* Vbase = (const char*)smem + 16384 + cur * 8192;

    // K frags for this wave's kv-half (swizzled read)
    bf16x8 kc[4];
#pragma unroll
    for (int t = 0; t < 4; t++) {
      const int row = wk * 32 + l31;
      const int u = (t * 2 + hi) ^ (l31 & 7);
      kc[t] = *(const bf16x8*)(Kbase + row * 128 + u * 16);
    }

    // S^T (one 32x32 tile) = K_half · Q^T over d=64 (log2-scaled already)
    f32x16 s = {};
    __builtin_amdgcn_s_setprio(1);
#pragma unroll
    for (int t = 0; t < 4; t++)
      s = __builtin_amdgcn_mfma_f32_32x32x16_bf16(kc[t], qf[t], s, 0, 0, 0);
    __builtin_amdgcn_s_setprio(0);

    // raw row-max over the half (mask applied later by zeroing p), tree + partner
    float mx[8];
#pragma unroll
    for (int i = 0; i < 8; i++) mx[i] = fmaxf(s[i], s[i + 8]);
    float m01 = fmaxf(mx[0], mx[1]), m23 = fmaxf(mx[2], mx[3]);
    float m45 = fmaxf(mx[4], mx[5]), m67 = fmaxf(mx[6], mx[7]);
    float pm = fmaxf(fmaxf(m01, m23), fmaxf(m45, m67));
    pm = fmaxf(pm, __shfl_xor(pm, 32, 64));

    // deferred rescale (THR=8 in log2 domain -> p bounded by 256)
    if (__any(pm > m_run + 8.f)) {
      float mn = fmaxf(m_run, pm);
      float fs = exp2_fast(m_run - mn);
      m_run = mn;
      lsum *= fs;
      acc0 *= fs;
      acc1 *= fs;
    }

    // p = exp2(s - m), mask-zero (this wave's 32-bit mask half), pack kv-pairs
    u32 msel = wk ? (u32)(mw >> 32) : (u32)mw;
    u32 wsh = msel >> (4 * hi);
    u32 wwd[8];
#pragma unroll
    for (int p = 0; p < 8; p++) {
      const int r0 = 2 * p;
      const int sh = (r0 & 3) + 8 * (p >> 1);  // kv_local - 4*hi for reg r0
      float a0 = exp2_fast(s[r0] - m_run);
      float a1 = exp2_fast(s[r0 + 1] - m_run);
      a0 = ((wsh >> sh) & 1u) ? a0 : 0.f;
      a1 = ((wsh >> (sh + 1)) & 1u) ? a1 : 0.f;
      lsum += a0 + a1;
      wwd[p] = (u32)f2b(a0) | ((u32)f2b(a1) << 16);
    }

    // V frags for this wave's kv-half (on-demand: short live range)
    bf16x8 va[2][2];
#pragma unroll
    for (int dt = 0; dt < 2; dt++)
#pragma unroll
      for (int kk = 0; kk < 2; kk++) {
        const int row = dt * 32 + l31;
        const int u = (wk * 4 + kk * 2 + hi) ^ (l31 & 7);
        va[dt][kk] = *(const bf16x8*)(Vbase + row * 128 + u * 16);
      }

    // PV: B-frags via in-register half-exchange (validated r9/r10), kk over 2 k-slices
    __builtin_amdgcn_s_setprio(1);
#pragma unroll
    for (int kk = 0; kk < 2; kk++) {
      const int b4 = kk * 4;
      u32 a0w = wwd[b4 + 0], a1w = wwd[b4 + 1], a2w = wwd[b4 + 2], a3w = wwd[b4 + 3];
      u32 e0 = __shfl_xor(hi ? a0w : a2w, 32, 64);
      u32 e1 = __shfl_xor(hi ? a1w : a3w, 32, 64);
      u32 f0 = hi ? e0 : a0w;
      u32 f1 = hi ? e1 : a1w;
      u32 f2c = hi ? a2w : e0;
      u32 f3 = hi ? a3w : e1;
      u32x4v pv4 = {f0, f1, f2c, f3};
      bf16x8 pbf = __builtin_bit_cast(bf16x8, pv4);
      acc0 = __builtin_amdgcn_mfma_f32_32x32x16_bf16(va[0][kk], pbf, acc0, 0, 0, 0);
      acc1 = __builtin_amdgcn_mfma_f32_32x32x16_bf16(va[1][kk], pbf, acc1, 0, 0, 0);
    }
    __builtin_amdgcn_s_setprio(0);

    mw = mw_n;
    cur ^= 1;
  }

  // ---- in-block merge of kv-half partials (comb overlays dead K/V LDS) ----
  lsum += __shfl_xor(lsum, 32, 64);  // combine hi halves: lsum now per-q total for this half
  __syncthreads();                   // all K/V reads done before comb overwrites
  float* comb = (float*)smem;        // [2][34][64] f32 = 17.4KB
  float* cb = comb + wq * 34 * 64;
  if (wk == 1) {
    cb[0 * 64 + lane] = m_run;
    cb[1 * 64 + lane] = lsum;
#pragma unroll
    for (int r = 0; r < 16; r++) {
      cb[(2 + r) * 64 + lane]  = acc0[r];
      cb[(18 + r) * 64 + lane] = acc1[r];
    }
  }
  __syncthreads();
  if (wk == 0) {
    float mB = cb[0 * 64 + lane];
    float lB_ = cb[1 * 64 + lane];
    float mT = fmaxf(m_run, mB);
    float fA = exp2_fast(m_run - mT);
    float fB = exp2_fast(mB - mT);
    float lt = lsum * fA + lB_ * fB;
    float ia = fA / lt, ib = fB / lt;
#pragma unroll
    for (int r = 0; r < 16; r++) {
      acc0[r] = acc0[r] * ia + cb[(2 + r) * 64 + lane] * ib;
      acc1[r] = acc1[r] * ia + cb[(18 + r) * 64 + lane] * ib;
    }
    u16* orow = attnb + ((size_t)b * 2048 + q) * 1024 + h * 64;
#pragma unroll
    for (int rq = 0; rq < 4; rq++) {
      const int rb = rq * 4;
      {
        u32 lo = (u32)f2b(acc0[rb]) | ((u32)f2b(acc0[rb + 1]) << 16);
        u32 hi2 = (u32)f2b(acc0[rb + 2]) | ((u32)f2b(acc0[rb + 3]) << 16);
        uint2 st; st.x = lo; st.y = hi2;
        *(uint2*)(orow + 8 * rq + 4 * hi) = st;
      }
      {
        u32 lo = (u32)f2b(acc1[rb]) | ((u32)f2b(acc1[rb + 1]) << 16);
        u32 hi2 = (u32)f2b(acc1[rb + 2]) | ((u32)f2b(acc1[rb + 3]) << 16);
        uint2 st; st.x = lo; st.y = hi2;
        *(uint2*)(orow + 32 + 8 * rq + 4 * hi) = st;
      }
    }
  }
}

extern "C" void kernel_launch(void* const* d_in, const int* in_sizes, int n_in,
                              void* d_out, int out_size, void* d_ws, size_t ws_size,
                              hipStream_t stream) {
  const float* x    = (const float*)d_in[0];
  const int*   mask = (const int*)d_in[1];
  const float* Wqkv = (const float*)d_in[2];
  const float* Wout = (const float*)d_in[3];
  const float* bout = (const float*)d_in[4];
  float* out = (float*)d_out;

  char* ws = (char*)d_ws;
  // layout (bytes): [0,8M) xb / attnb; [8,14M) Wqkv_t; [14,16M) Wout_t; [16,16.5M) mbits;
  // [17,25M) Qb; [25,33M) Kb; [33,41M) Vt
  u16* xb     = (u16*)(ws);
  u16* attnb  = xb;
  u16* Wqkv_t = (u16*)(ws + (size_t)(8u << 20));
  u16* Wout_t = (u16*)(ws + (size_t)(14u << 20));
  u64* mbits  = (u64*)(ws + (size_t)(16u << 20));
  u16* Qb     = (u16*)(ws + (size_t)(17u << 20));
  u16* Kb     = (u16*)(ws + (size_t)(25u << 20));
  u16* Vt     = (u16*)(ws + (size_t)(33u << 20));

  // 1) fused prep: maskbits + cast + both weight transposes (one launch)
  prep_kernel<<<24576, 256, 0, stream>>>(x, mask, Wqkv, Wout, xb, mbits, Wqkv_t, Wout_t);
  // 2) QKV GEMM + head-split scatter
  gemm_qkv_kernel<<<dim3(24, 32), 256, 0, stream>>>(xb, Wqkv_t, Qb, Kb, Vt);
  // 3) flash attention
  attn_kernel<<<dim3(32, 32), 256, 0, stream>>>(Qb, Kb, Vt, mbits, attnb);
  // 4) out projection + bias
  gemm_out_kernel<<<dim3(8, 64), 256, 0, stream>>>(attnb, Wout_t, bout, out);
}

// Round 14
// 143.365 us; speedup vs baseline: 1.3521x; 1.0320x over previous
//
#include <hip/hip_runtime.h>
#include <hip/hip_bf16.h>

typedef __bf16 bf16x8 __attribute__((ext_vector_type(8)));
typedef float f32x4 __attribute__((ext_vector_type(4)));
typedef float f32x16 __attribute__((ext_vector_type(16)));
typedef unsigned short u16;
typedef unsigned int u32;
typedef unsigned long long u64;
typedef u32 u32x4v __attribute__((ext_vector_type(4)));

#define QSCALE 0.18033688011112042f  /* log2(e)/8 : folds SCALE and exp->exp2 into Q */

__device__ __forceinline__ u16 f2b(float x) {
  __hip_bfloat16 h = __float2bfloat16(x);
  return __builtin_bit_cast(u16, h);
}

// HW packed f32->bf16 (RNE): vdst.lo = bf16(a), vdst.hi = bf16(b).
// Replaces ~10 VALU ops of software RNE per pair with 1 instruction.
__device__ __forceinline__ u32 cvtpk_bf16(float a, float b) {
  u32 r;
  asm("v_cvt_pk_bf16_f32 %0, %1, %2" : "=v"(r) : "v"(a), "v"(b));
  return r;
}

__device__ __forceinline__ float exp2_fast(float x) {
#if __has_builtin(__builtin_amdgcn_exp2f)
  return __builtin_amdgcn_exp2f(x);
#else
  float r; asm("v_exp_f32 %0, %1" : "=v"(r) : "v"(x)); return r;
#endif
}

// async global->LDS, 16B per lane; LDS dest = wave-uniform base + lane*16
__device__ __forceinline__ void gload_lds16(const void* g, void* l) {
  __builtin_amdgcn_global_load_lds((const __attribute__((address_space(1))) u32*)g,
                                   (__attribute__((address_space(3))) u32*)l, 16, 0, 0);
}

// ---------------- fused preprocessing: maskbits | cast | transpose Wqkv | transpose Wout ----
// One launch replaces 4 (saves ~3 graph-replay gaps). Branch is block-uniform.
__global__ __launch_bounds__(256) void prep_kernel(const float* __restrict__ x,
                                                   const int* __restrict__ mask,
                                                   const float* __restrict__ Wqkv,
                                                   const float* __restrict__ Wout,
                                                   u16* __restrict__ xb,
                                                   u64* __restrict__ mbits,
                                                   u16* __restrict__ Wqkv_t,
                                                   u16* __restrict__ Wout_t) {
  const int bid = blockIdx.x, tid = threadIdx.x;
  if (bid < 16384) {
    // maskbits
    int gtid = bid * 256 + tid;
    int wid = gtid >> 6, lane = gtid & 63;
    int v = mask[(size_t)wid * 64 + lane];
    u64 b = __ballot(v != 0);
    if (lane == 0) mbits[wid] = b;
    return;
  }
  if (bid < 20480) {
    // cast x -> bf16
    int i = (bid - 16384) * 256 + tid;
    float4 v = ((const float4*)x)[i];
    ushort4 o;
    o.x = f2b(v.x); o.y = f2b(v.y); o.z = f2b(v.z); o.w = f2b(v.w);
    ((ushort4*)xb)[i] = o;
    return;
  }
  // transpose+cast branch (block-uniform; __syncthreads safe)
  __shared__ float t[32][33];
  const float* src; u16* dst; int R, C, c0, r0;
  if (bid < 23552) {
    int local = bid - 20480;            // 96 x 32 tiles
    src = Wqkv; dst = Wqkv_t; R = 1024; C = 3072;
    c0 = (local % 96) * 32; r0 = (local / 96) * 32;
  } else {
    int local = bid - 23552;            // 32 x 32 tiles
    src = Wout; dst = Wout_t; R = 1024; C = 1024;
    c0 = (local % 32) * 32; r0 = (local / 32) * 32;
  }
  const int tx = tid & 31, ty = tid >> 5;   // (32, 8)
  for (int k = 0; k < 32; k += 8)
    t[ty + k][tx] = src[(size_t)(r0 + ty + k) * C + c0 + tx];
  __syncthreads();
  for (int k = 0; k < 32; k += 8)
    dst[(size_t)(c0 + ty + k) * R + r0 + tx] = f2b(t[tx][ty + k]);
}

// ---------------- QKV GEMM: xb[4096][1024] @ Wqkv_t[3072][1024]^T ----------------
// m97 structure: global_load_lds(16B) staging, 2 barriers per K-step.
// Epilogue scatters into Qb (pre-scaled by QSCALE) / Kb [B][H][N][64], Vt [B][H][64][N].
__global__ __launch_bounds__(256) void gemm_qkv_kernel(const u16* __restrict__ A,
                                                       const u16* __restrict__ Bt,
                                                       u16* __restrict__ Qb,
                                                       u16* __restrict__ Kb,
                                                       u16* __restrict__ Vt) {
  __shared__ u16 lA[128 * 32], lB[128 * 32];
  const int tid = threadIdx.x, lane = tid & 63, w = tid >> 6;
  const int wr = w >> 1, wc = w & 1, lrow = lane & 15, lk = lane >> 4;
  const int bm = blockIdx.y, bn = blockIdx.x;
  const int srow = tid >> 2, scol = (tid & 3) * 8;
  const u16* Arow = A + (size_t)(bm * 128 + srow) * 1024 + scol;
  const u16* Brow = Bt + (size_t)(bn * 128 + srow) * 1024 + scol;
  f32x4 acc[4][4] = {};
  for (int k0 = 0; k0 < 1024; k0 += 32) {
    __syncthreads();  // prior iteration's ds_reads done before overwrite
    gload_lds16(Arow + k0,             (char*)lA + w * 1024);
    gload_lds16(Arow + 64 * 1024 + k0, (char*)lA + 4096 + w * 1024);
    gload_lds16(Brow + k0,             (char*)lB + w * 1024);
    gload_lds16(Brow + 64 * 1024 + k0, (char*)lB + 4096 + w * 1024);
    __syncthreads();  // drains vmcnt: staged data visible
    bf16x8 af[4], bfr[4];
    for (int mi = 0; mi < 4; mi++)
      af[mi] = *(const bf16x8*)&lA[(wr * 64 + mi * 16 + lrow) * 32 + lk * 8];
    for (int ni = 0; ni < 4; ni++)
      bfr[ni] = *(const bf16x8*)&lB[(wc * 64 + ni * 16 + lrow) * 32 + lk * 8];
    for (int mi = 0; mi < 4; mi++)
      for (int ni = 0; ni < 4; ni++)
        acc[mi][ni] = __builtin_amdgcn_mfma_f32_16x16x32_bf16(af[mi], bfr[ni], acc[mi][ni], 0, 0, 0);
  }
  const int rowbase = bm * 128 + wr * 64;
  const int colbase = bn * 128 + wc * 64;
  for (int mi = 0; mi < 4; mi++)
    for (int ni = 0; ni < 4; ni++)
      for (int r = 0; r < 4; r++) {
        int row = rowbase + mi * 16 + lk * 4 + r;
        int col = colbase + ni * 16 + lrow;
        int b = row >> 11, n = row & 2047;
        int which = col >> 10, within = col & 1023;
        int h = within >> 6, d = within & 63;
        float av = acc[mi][ni][r];
        size_t bh = (size_t)(b * 16 + h);
        if (which == 0)      Qb[(bh * 2048 + n) * 64 + d] = f2b(av * QSCALE);
        else if (which == 1) Kb[(bh * 2048 + n) * 64 + d] = f2b(av);
        else                 Vt[(bh * 64 + d) * 2048 + n] = f2b(av);
      }
}

// ---------------- out-proj GEMM: attnb[4096][1024] @ Wout_t[1024][1024]^T + bias ----
// 64(M)x128(N) tile, grid (8, 64) = 512 blocks (2/CU). A = 1 gload/wave, B = 2.
__global__ __launch_bounds__(256) void gemm_out_kernel(const u16* __restrict__ A,
                                                       const u16* __restrict__ Bt,
                                                       const float* __restrict__ bias,
                                                       float* __restrict__ out) {
  __shared__ u16 lA[64 * 32], lB[128 * 32];
  const int tid = threadIdx.x, lane = tid & 63, w = tid >> 6;
  const int wr = w >> 1, wc = w & 1, lrow = lane & 15, lk = lane >> 4;
  const int bn = blockIdx.x, bm = blockIdx.y;
  const u16* Arow  = A  + (size_t)(bm * 64 + w * 16 + (lane >> 2)) * 1024 + (lane & 3) * 8;
  const u16* Brow0 = Bt + (size_t)(bn * 128 + (w * 2) * 16 + (lane >> 2)) * 1024 + (lane & 3) * 8;
  const u16* Brow1 = Brow0 + 16 * 1024;
  f32x4 acc[2][4] = {};
  for (int k0 = 0; k0 < 1024; k0 += 32) {
    __syncthreads();
    gload_lds16(Arow + k0,  (char*)lA + w * 1024);
    gload_lds16(Brow0 + k0, (char*)lB + (w * 2) * 1024);
    gload_lds16(Brow1 + k0, (char*)lB + (w * 2 + 1) * 1024);
    __syncthreads();
    bf16x8 af[2], bfr[4];
    for (int mi = 0; mi < 2; mi++)
      af[mi] = *(const bf16x8*)&lA[(wr * 32 + mi * 16 + lrow) * 32 + lk * 8];
    for (int ni = 0; ni < 4; ni++)
      bfr[ni] = *(const bf16x8*)&lB[(wc * 64 + ni * 16 + lrow) * 32 + lk * 8];
    for (int mi = 0; mi < 2; mi++)
      for (int ni = 0; ni < 4; ni++)
        acc[mi][ni] = __builtin_amdgcn_mfma_f32_16x16x32_bf16(af[mi], bfr[ni], acc[mi][ni], 0, 0, 0);
  }
  const int rowbase = bm * 64 + wr * 32;
  const int colbase = bn * 128 + wc * 64;
  for (int mi = 0; mi < 2; mi++)
    for (int ni = 0; ni < 4; ni++)
      for (int r = 0; r < 4; r++) {
        int row = rowbase + mi * 16 + lk * 4 + r;
        int col = colbase + ni * 16 + lrow;
        out[(size_t)row * 1024 + col] = acc[mi][ni][r] + bias[col];
      }
}

// ---------------- flash attention: swapped QK^T (32x32), kv-half wave split ----
// grid (32, 32), block 256 = 4 waves: wave = (wq = w&1 q-tile, wk = w>>1 kv-half).
// Block covers 64 q-rows, sweeps all 2048 kv in 32 chunks of 64; wave handles the
// 32-kv half of each chunk for its q-tile. Partner waves merge via comb LDS overlay.
// r14 change: P-pack via v_cvt_pk_bf16_f32 (1 instr/pair vs ~10 of SW RNE) — the
// pack was ~25-30% of the chunk's VALU work (VALUBusy 62.7% @ 78us).
__global__ __launch_bounds__(256, 3) void attn_kernel(const u16* __restrict__ Qb,
                                                      const u16* __restrict__ Kb,
                                                      const u16* __restrict__ Vt,
                                                      const u64* __restrict__ Mb,
                                                      u16* __restrict__ attnb) {
  // 32KB: [0,8K) Kbuf0, [8K,16K) Kbuf1, [16K,24K) Vbuf0, [24K,32K) Vbuf1.
  // comb (f32 [2][34][64] = 17.4KB) overlays [0,17.4K) after the kv sweep.
  __shared__ u32 smem[8192];
  const int tid = threadIdx.x, lane = tid & 63, w = tid >> 6;
  const int l31 = lane & 31, hi = lane >> 5;
  const int wq = w & 1, wk = w >> 1;
  const int qt = blockIdx.x, bh = blockIdx.y;
  const int h = bh & 15, b = bh >> 4;
  const int q = qt * 64 + wq * 32 + l31;
  const u16* Qp = Qb + (size_t)bh * 2048 * 64;
  const u16* Kp = Kb + (size_t)bh * 2048 * 64;
  const u16* Vp = Vt + (size_t)bh * 64 * 2048;
  const u64* Mrow = Mb + (size_t)q * 32;

  // staging: wave w covers rows [16w,16w+16) of both K and V^T tiles (4 instrs),
  // role-independent. XOR-swizzle via pre-swizzled source (rule #21 both-sides).
  const int rsub = lane >> 3;                       // 0..7
  const int usrc = ((lane & 7) ^ rsub) * 8;         // pre-swizzled source 16B unit
  auto stage = [&](int bi, int j0) {
#pragma unroll
    for (int j = 0; j < 2; j++) {
      const int i = w * 2 + j;                      // instr index 0..7
      const int row = 8 * i + rsub;
      gload_lds16(Kp + (size_t)(j0 + row) * 64 + usrc, (char*)smem + bi * 8192 + i * 1024);
      gload_lds16(Vp + (size_t)row * 2048 + j0 + usrc, (char*)smem + 16384 + bi * 8192 + i * 1024);
    }
  };

  // Q B-frags: col=q=lane&31, k-half by hi; resident whole kernel
  bf16x8 qf[4];
#pragma unroll
  for (int t = 0; t < 4; t++)
    qf[t] = *(const bf16x8*)&Qp[(size_t)q * 64 + t * 16 + hi * 8];

  f32x16 acc0 = {}, acc1 = {};  // O^T partial (this wave's kv-half): d [0,32)/[32,64), col=q
  float m_run = -3.0e38f, lsum = 0.f;

  stage(0, 0);
  u64 mw = Mrow[0];
  int cur = 0;

  for (int c = 0; c < 32; c++) {
    __syncthreads();  // drains vmcnt: buf[cur] staged; prior reads of buf[cur^1] done
    if (c + 1 < 32) stage(cur ^ 1, (c + 1) * 64);
    u64 mw_n = (c + 1 < 32) ? Mrow[c + 1] : 0;

    const char* Kbase = (const char*)smem + cur * 8192;
    const char* Vbase = (const char*)smem + 16384 + cur * 8192;

    // K frags for this wave's kv-half (swizzled read)
    bf16x8 kc[4];
#pragma unroll
    for (int t = 0; t < 4; t++) {
      const int row = wk * 32 + l31;
      const int u = (t * 2 + hi) ^ (l31 & 7);
      kc[t] = *(const bf16x8*)(Kbase + row * 128 + u * 16);
    }

    // S^T (one 32x32 tile) = K_half · Q^T over d=64 (log2-scaled already)
    f32x16 s = {};
    __builtin_amdgcn_s_setprio(1);
#pragma unroll
    for (int t = 0; t < 4; t++)
      s = __builtin_amdgcn_mfma_f32_32x32x16_bf16(kc[t], qf[t], s, 0, 0, 0);
    __builtin_amdgcn_s_setprio(0);

    // raw row-max over the half (mask applied later by zeroing p), tree + partner
    float mx[8];
#pragma unroll
    for (int i = 0; i < 8; i++) mx[i] = fmaxf(s[i], s[i + 8]);
    float m01 = fmaxf(mx[0], mx[1]), m23 = fmaxf(mx[2], mx[3]);
    float m45 = fmaxf(mx[4], mx[5]), m67 = fmaxf(mx[6], mx[7]);
    float pm = fmaxf(fmaxf(m01, m23), fmaxf(m45, m67));
    pm = fmaxf(pm, __shfl_xor(pm, 32, 64));

    // deferred rescale (THR=8 in log2 domain -> p bounded by 256)
    if (__any(pm > m_run + 8.f)) {
      float mn = fmaxf(m_run, pm);
      float fs = exp2_fast(m_run - mn);
      m_run = mn;
      lsum *= fs;
      acc0 *= fs;
      acc1 *= fs;
    }

    // p = exp2(s - m), mask-zero (this wave's 32-bit mask half), pack via HW cvt_pk
    u32 msel = wk ? (u32)(mw >> 32) : (u32)mw;
    u32 wsh = msel >> (4 * hi);
    u32 wwd[8];
#pragma unroll
    for (int p = 0; p < 8; p++) {
      const int r0 = 2 * p;
      const int sh = (r0 & 3) + 8 * (p >> 1);  // kv_local - 4*hi for reg r0
      float a0 = exp2_fast(s[r0] - m_run);
      float a1 = exp2_fast(s[r0 + 1] - m_run);
      a0 = ((wsh >> sh) & 1u) ? a0 : 0.f;
      a1 = ((wsh >> (sh + 1)) & 1u) ? a1 : 0.f;
      lsum += a0 + a1;
      wwd[p] = cvtpk_bf16(a0, a1);
    }

    // V frags for this wave's kv-half (on-demand: short live range)
    bf16x8 va[2][2];
#pragma unroll
    for (int dt = 0; dt < 2; dt++)
#pragma unroll
      for (int kk = 0; kk < 2; kk++) {
        const int row = dt * 32 + l31;
        const int u = (wk * 4 + kk * 2 + hi) ^ (l31 & 7);
        va[dt][kk] = *(const bf16x8*)(Vbase + row * 128 + u * 16);
      }

    // PV: B-frags via in-register half-exchange (validated r9/r10), kk over 2 k-slices
    __builtin_amdgcn_s_setprio(1);
#pragma unroll
    for (int kk = 0; kk < 2; kk++) {
      const int b4 = kk * 4;
      u32 a0w = wwd[b4 + 0], a1w = wwd[b4 + 1], a2w = wwd[b4 + 2], a3w = wwd[b4 + 3];
      u32 e0 = __shfl_xor(hi ? a0w : a2w, 32, 64);
      u32 e1 = __shfl_xor(hi ? a1w : a3w, 32, 64);
      u32 f0 = hi ? e0 : a0w;
      u32 f1 = hi ? e1 : a1w;
      u32 f2c = hi ? a2w : e0;
      u32 f3 = hi ? a3w : e1;
      u32x4v pv4 = {f0, f1, f2c, f3};
      bf16x8 pbf = __builtin_bit_cast(bf16x8, pv4);
      acc0 = __builtin_amdgcn_mfma_f32_32x32x16_bf16(va[0][kk], pbf, acc0, 0, 0, 0);
      acc1 = __builtin_amdgcn_mfma_f32_32x32x16_bf16(va[1][kk], pbf, acc1, 0, 0, 0);
    }
    __builtin_amdgcn_s_setprio(0);

    mw = mw_n;
    cur ^= 1;
  }

  // ---- in-block merge of kv-half partials (comb overlays dead K/V LDS) ----
  lsum += __shfl_xor(lsum, 32, 64);  // combine hi halves: lsum now per-q total for this half
  __syncthreads();                   // all K/V reads done before comb overwrites
  float* comb = (float*)smem;        // [2][34][64] f32 = 17.4KB
  float* cb = comb + wq * 34 * 64;
  if (wk == 1) {
    cb[0 * 64 + lane] = m_run;
    cb[1 * 64 + lane] = lsum;
#pragma unroll
    for (int r = 0; r < 16; r++) {
      cb[(2 + r) * 64 + lane]  = acc0[r];
      cb[(18 + r) * 64 + lane] = acc1[r];
    }
  }
  __syncthreads();
  if (wk == 0) {
    float mB = cb[0 * 64 + lane];
    float lB_ = cb[1 * 64 + lane];
    float mT = fmaxf(m_run, mB);
    float fA = exp2_fast(m_run - mT);
    float fB = exp2_fast(mB - mT);
    float lt = lsum * fA + lB_ * fB;
    float ia = fA / lt, ib = fB / lt;
#pragma unroll
    for (int r = 0; r < 16; r++) {
      acc0[r] = acc0[r] * ia + cb[(2 + r) * 64 + lane] * ib;
      acc1[r] = acc1[r] * ia + cb[(18 + r) * 64 + lane] * ib;
    }
    u16* orow = attnb + ((size_t)b * 2048 + q) * 1024 + h * 64;
#pragma unroll
    for (int rq = 0; rq < 4; rq++) {
      const int rb = rq * 4;
      {
        uint2 st;
        st.x = cvtpk_bf16(acc0[rb], acc0[rb + 1]);
        st.y = cvtpk_bf16(acc0[rb + 2], acc0[rb + 3]);
        *(uint2*)(orow + 8 * rq + 4 * hi) = st;
      }
      {
        uint2 st;
        st.x = cvtpk_bf16(acc1[rb], acc1[rb + 1]);
        st.y = cvtpk_bf16(acc1[rb + 2], acc1[rb + 3]);
        *(uint2*)(orow + 32 + 8 * rq + 4 * hi) = st;
      }
    }
  }
}

extern "C" void kernel_launch(void* const* d_in, const int* in_sizes, int n_in,
                              void* d_out, int out_size, void* d_ws, size_t ws_size,
                              hipStream_t stream) {
  const float* x    = (const float*)d_in[0];
  const int*   mask = (const int*)d_in[1];
  const float* Wqkv = (const float*)d_in[2];
  const float* Wout = (const float*)d_in[3];
  const float* bout = (const float*)d_in[4];
  float* out = (float*)d_out;

  char* ws = (char*)d_ws;
  // layout (bytes): [0,8M) xb / attnb; [8,14M) Wqkv_t; [14,16M) Wout_t; [16,16.5M) mbits;
  // [17,25M) Qb; [25,33M) Kb; [33,41M) Vt
  u16* xb     = (u16*)(ws);
  u16* attnb  = xb;
  u16* Wqkv_t = (u16*)(ws + (size_t)(8u << 20));
  u16* Wout_t = (u16*)(ws + (size_t)(14u << 20));
  u64* mbits  = (u64*)(ws + (size_t)(16u << 20));
  u16* Qb     = (u16*)(ws + (size_t)(17u << 20));
  u16* Kb     = (u16*)(ws + (size_t)(25u << 20));
  u16* Vt     = (u16*)(ws + (size_t)(33u << 20));

  // 1) fused prep: maskbits + cast + both weight transposes (one launch)
  prep_kernel<<<24576, 256, 0, stream>>>(x, mask, Wqkv, Wout, xb, mbits, Wqkv_t, Wout_t);
  // 2) QKV GEMM + head-split scatter
  gemm_qkv_kernel<<<dim3(24, 32), 256, 0, stream>>>(xb, Wqkv_t, Qb, Kb, Vt);
  // 3) flash attention
  attn_kernel<<<dim3(32, 32), 256, 0, stream>>>(Qb, Kb, Vt, mbits, attnb);
  // 4) out projection + bias
  gemm_out_kernel<<<dim3(8, 64), 256, 0, stream>>>(attnb, Wout_t, bout, out);
}